// Round 1
// baseline (323.176 us; speedup 1.0000x reference)
//
#include <hip/hip_runtime.h>
#include <hip/hip_bf16.h>
#include <stdint.h>

typedef unsigned short u16;
typedef short short8 __attribute__((ext_vector_type(8)));
typedef float f32x4 __attribute__((ext_vector_type(4)));
typedef u16 u16x4 __attribute__((ext_vector_type(4)));

#define LOG2E 1.4426950408889634f

// fp32 -> bf16 RNE (values are finite; no NaN handling needed)
static __device__ __forceinline__ u16 f2bf(float f) {
  unsigned u = __float_as_uint(f);
  unsigned rnd = 0x7fffu + ((u >> 16) & 1u);
  return (u16)((u + rnd) >> 16);
}

static __device__ __forceinline__ void gload_lds16(const void* g, void* l) {
  __builtin_amdgcn_global_load_lds(
      (const __attribute__((address_space(1))) unsigned int*)g,
      (__attribute__((address_space(3))) unsigned int*)l, 16, 0, 0);
}

// ---------------------------------------------------------------- converts
__global__ __launch_bounds__(256) void cvt_hs_kernel(const float4* __restrict__ src,
                                                     u16x4* __restrict__ dst) {
  int i = blockIdx.x * 256 + threadIdx.x;   // 4096*256 = 1M float4 = 4M floats
  float4 v = src[i];
  u16x4 o;
  o[0] = f2bf(v.x); o[1] = f2bf(v.y); o[2] = f2bf(v.z); o[3] = f2bf(v.w);
  dst[i] = o;
}

// W [1024][1024] fp32 (k-major rows) -> WT [1024][1024] bf16 (n-major rows, k contiguous)
__global__ __launch_bounds__(256) void cvt_transpose_kernel(
    const float* __restrict__ Wq, const float* __restrict__ Wk,
    const float* __restrict__ Wv, const float* __restrict__ Wo,
    u16* __restrict__ WT) {
  __shared__ float tile[32][33];
  const int z = blockIdx.z;
  const float* src = (z == 0) ? Wq : (z == 1) ? Wk : (z == 2) ? Wv : Wo;
  u16* dst = WT + (size_t)z * 1024 * 1024;
  const int row0 = blockIdx.y * 32, col0 = blockIdx.x * 32;
  const int tx = threadIdx.x, ty = threadIdx.y;  // (32, 8)
#pragma unroll
  for (int i = 0; i < 4; ++i)
    tile[ty + i * 8][tx] = src[(size_t)(row0 + ty + i * 8) * 1024 + col0 + tx];
  __syncthreads();
#pragma unroll
  for (int i = 0; i < 4; ++i) {
    int r = ty + i * 8;
    dst[(size_t)(col0 + r) * 1024 + row0 + tx] = f2bf(tile[tx][r]);
  }
}

// tree_mask [2048][2048] int32 -> bits [2048][32] uint64
__global__ __launch_bounds__(256) void mask_bits_kernel(const int* __restrict__ mask,
                                                        unsigned long long* __restrict__ bits) {
  int gw = blockIdx.x * 4 + (threadIdx.x >> 6);  // 0..65535
  int lane = threadIdx.x & 63;
  int q = gw >> 5, w = gw & 31;
  int mv = mask[(size_t)q * 2048 + w * 64 + lane];
  unsigned long long bal = __ballot(mv != 0);
  if (lane == 0) bits[(size_t)q * 32 + w] = bal;
}

// ---------------------------------------------------------------- GEMM QKV
// X [4096][1024] bf16 ; WT [3072][1024] bf16 (row n = col of [Wq|Wk|Wv], k contiguous)
// out: Q/K/V [2][16][2048][64] bf16
__global__ __launch_bounds__(256) void gemm_qkv_kernel(
    const u16* __restrict__ X, const u16* __restrict__ WT,
    const float* __restrict__ bq, const float* __restrict__ bk, const float* __restrict__ bv,
    u16* __restrict__ Qb, u16* __restrict__ Kb, u16* __restrict__ Vb) {
  __shared__ u16 As[128 * 32];
  __shared__ u16 Bs[128 * 32];
  const int tid = threadIdx.x;
  const int lane = tid & 63, wid = tid >> 6;
  const int l15 = lane & 15, lg = lane >> 4;
  const int n0 = blockIdx.x * 128, m0 = blockIdx.y * 128;
  const int wr = wid >> 1, wc = wid & 1;

  f32x4 acc[4][4] = {};

  for (int kt = 0; kt < 32; ++kt) {
    __syncthreads();
#pragma unroll
    for (int p = 0; p < 2; ++p) {
      const int c = p * 256 + tid;
      const int r = c >> 2, ch = c & 3;
      gload_lds16(X + (size_t)(m0 + r) * 1024 + kt * 32 + ch * 8,
                  &As[(p * 256 + wid * 64) * 8]);
      gload_lds16(WT + (size_t)(n0 + r) * 1024 + kt * 32 + ch * 8,
                  &Bs[(p * 256 + wid * 64) * 8]);
    }
    __syncthreads();
    short8 af[4], bfr[4];
#pragma unroll
    for (int i = 0; i < 4; ++i) {
      af[i] = *reinterpret_cast<const short8*>(&As[(wr * 64 + i * 16 + l15) * 32 + lg * 8]);
      bfr[i] = *reinterpret_cast<const short8*>(&Bs[(wc * 64 + i * 16 + l15) * 32 + lg * 8]);
    }
#pragma unroll
    for (int i = 0; i < 4; ++i)
#pragma unroll
      for (int j = 0; j < 4; ++j)
        acc[i][j] = __builtin_amdgcn_mfma_f32_16x16x32_bf16(af[i], bfr[j], acc[i][j], 0, 0, 0);
  }

#pragma unroll
  for (int j = 0; j < 4; ++j) {
    const int n = n0 + wc * 64 + j * 16 + l15;       // 0..3071
    const float bias = (n < 1024) ? bq[n] : (n < 2048) ? bk[n - 1024] : bv[n - 2048];
    u16* dst = (n < 1024) ? Qb : (n < 2048) ? Kb : Vb;
    const int nl = n & 1023;
    const int hh = nl >> 6, d = nl & 63;
#pragma unroll
    for (int i = 0; i < 4; ++i) {
#pragma unroll
      for (int r = 0; r < 4; ++r) {
        const int m = m0 + wr * 64 + i * 16 + lg * 4 + r;   // 0..4095
        const int bb = m >> 11, t = m & 2047;
        dst[((size_t)(bb * 16 + hh) * 2048 + t) * 64 + d] = f2bf(acc[i][j][r] + bias);
      }
    }
  }
}

// ---------------------------------------------------------------- attention
// Q/K/V [2][16][2048][64] bf16 ; MB [2048][32] uint64 ; AO [4096][1024] bf16
__global__ __launch_bounds__(256) void attn_kernel(
    const u16* __restrict__ Q, const u16* __restrict__ K, const u16* __restrict__ V,
    const unsigned long long* __restrict__ MB, u16* __restrict__ AO) {
  __shared__ u16 k_lds[32][72];    // K tile, rows padded (+8 bf16) for bank spread
  __shared__ u16 vT_lds[64][40];   // V^T tile
  __shared__ u16 p_lds[4][16][40]; // per-wave P staging

  const int tid = threadIdx.x;
  const int wid = tid >> 6;
  const int lane = tid & 63;
  const int l15 = lane & 15;
  const int lg = lane >> 4;

  const int qt = blockIdx.x & 31;
  const int h = (blockIdx.x >> 5) & 15;
  const int b = blockIdx.x >> 9;
  const size_t bh_off = ((size_t)(b * 16 + h)) * 2048 * 64;

  // Q fragment (A-layout: row = lane&15, k = (lane>>4)*8.. contiguous)
  const int qa = qt * 64 + wid * 16 + l15;
  const short8* qp = reinterpret_cast<const short8*>(Q + bh_off + (size_t)qa * 64);
  const short8 qf0 = qp[lg];
  const short8 qf1 = qp[4 + lg];

  f32x4 O[4] = {};
  float mrow[4] = {-3e38f, -3e38f, -3e38f, -3e38f};
  float lrow[4] = {0.f, 0.f, 0.f, 0.f};

  const int qd = qt * 64 + wid * 16 + lg * 4;  // D-layout q-row base (add reg r)
  const int sr = tid >> 3;                     // staging row 0..31
  const int sc = tid & 7;                      // staging chunk 0..7

  for (int kt = 0; kt < 64; ++kt) {
    const int kbase = kt << 5;
    unsigned fields[4];
    int act = 0;
#pragma unroll
    for (int r = 0; r < 4; ++r) {
      unsigned long long w = MB[(size_t)(qd + r) * 32 + (kbase >> 6)];
      fields[r] = (unsigned)(w >> (kbase & 32));
      act |= (fields[r] != 0u);
    }
    if (!__syncthreads_or(act)) continue;  // full barrier; skip fully-masked tile

    {  // stage K tile and V^T tile (all 256 threads)
      const short8* kg = reinterpret_cast<const short8*>(K + bh_off + (size_t)(kbase + sr) * 64);
      short8 kv = kg[sc];
      *reinterpret_cast<short8*>(&k_lds[sr][sc * 8]) = kv;
      const short8* vg = reinterpret_cast<const short8*>(V + bh_off + (size_t)(kbase + sr) * 64);
      short8 vv = vg[sc];
#pragma unroll
      for (int j = 0; j < 8; ++j) vT_lds[sc * 8 + j][sr] = (u16)vv[j];
    }
    __syncthreads();

    if (__any(act)) {
      f32x4 s0 = {}, s1 = {};
#pragma unroll
      for (int ds = 0; ds < 2; ++ds) {
        short8 kf0 = *reinterpret_cast<const short8*>(&k_lds[l15][ds * 32 + lg * 8]);
        short8 kf1 = *reinterpret_cast<const short8*>(&k_lds[16 + l15][ds * 32 + lg * 8]);
        short8 qf = ds ? qf1 : qf0;
        s0 = __builtin_amdgcn_mfma_f32_16x16x32_bf16(qf, kf0, s0, 0, 0, 0);
        s1 = __builtin_amdgcn_mfma_f32_16x16x32_bf16(qf, kf1, s1, 0, 0, 0);
      }
#pragma unroll
      for (int r = 0; r < 4; ++r) {
        float v0 = ((fields[r] >> l15) & 1u) ? s0[r] * 0.125f : -1e30f;
        float v1 = ((fields[r] >> (16 + l15)) & 1u) ? s1[r] * 0.125f : -1e30f;
        float pm = fmaxf(v0, v1);
#pragma unroll
        for (int off = 1; off < 16; off <<= 1) pm = fmaxf(pm, __shfl_xor(pm, off));
        float mn = fmaxf(mrow[r], pm);
        float al = exp2f((mrow[r] - mn) * LOG2E);
        float e0 = exp2f((v0 - mn) * LOG2E);
        float e1 = exp2f((v1 - mn) * LOG2E);
        float rs = e0 + e1;
#pragma unroll
        for (int off = 1; off < 16; off <<= 1) rs += __shfl_xor(rs, off);
        lrow[r] = lrow[r] * al + rs;
        mrow[r] = mn;
        O[0][r] *= al; O[1][r] *= al; O[2][r] *= al; O[3][r] *= al;
        p_lds[wid][lg * 4 + r][l15] = f2bf(e0);
        p_lds[wid][lg * 4 + r][16 + l15] = f2bf(e1);
      }
      // read P back in A-layout (same-wave DS ordering; compiler inserts lgkmcnt)
      short8 pf = *reinterpret_cast<const short8*>(&p_lds[wid][l15][lg * 8]);
#pragma unroll
      for (int nf = 0; nf < 4; ++nf) {
        short8 vf = *reinterpret_cast<const short8*>(&vT_lds[nf * 16 + l15][lg * 8]);
        O[nf] = __builtin_amdgcn_mfma_f32_16x16x32_bf16(pf, vf, O[nf], 0, 0, 0);
      }
    }
  }

  const int mb = b * 2048 + qt * 64 + wid * 16 + lg * 4;
#pragma unroll
  for (int r = 0; r < 4; ++r) {
    float inv = (lrow[r] > 0.f) ? (1.0f / lrow[r]) : 0.f;
#pragma unroll
    for (int nf = 0; nf < 4; ++nf)
      AO[(size_t)(mb + r) * 1024 + h * 64 + nf * 16 + l15] = f2bf(O[nf][r] * inv);
  }
}

// ---------------------------------------------------------------- out GEMM
// A = AO [4096][1024] bf16 ; BT = WoT [1024][1024] bf16 ; out fp32 [4096][1024]
__global__ __launch_bounds__(256) void gemm_out_kernel(
    const u16* __restrict__ A, const u16* __restrict__ BT,
    const float* __restrict__ bo, float* __restrict__ out) {
  __shared__ u16 As[128 * 32];
  __shared__ u16 Bs[128 * 32];
  const int tid = threadIdx.x;
  const int lane = tid & 63, wid = tid >> 6;
  const int l15 = lane & 15, lg = lane >> 4;
  const int n0 = blockIdx.x * 128, m0 = blockIdx.y * 128;
  const int wr = wid >> 1, wc = wid & 1;

  f32x4 acc[4][4] = {};

  for (int kt = 0; kt < 32; ++kt) {
    __syncthreads();
#pragma unroll
    for (int p = 0; p < 2; ++p) {
      const int c = p * 256 + tid;
      const int r = c >> 2, ch = c & 3;
      gload_lds16(A + (size_t)(m0 + r) * 1024 + kt * 32 + ch * 8,
                  &As[(p * 256 + wid * 64) * 8]);
      gload_lds16(BT + (size_t)(n0 + r) * 1024 + kt * 32 + ch * 8,
                  &Bs[(p * 256 + wid * 64) * 8]);
    }
    __syncthreads();
    short8 af[4], bfr[4];
#pragma unroll
    for (int i = 0; i < 4; ++i) {
      af[i] = *reinterpret_cast<const short8*>(&As[(wr * 64 + i * 16 + l15) * 32 + lg * 8]);
      bfr[i] = *reinterpret_cast<const short8*>(&Bs[(wc * 64 + i * 16 + l15) * 32 + lg * 8]);
    }
#pragma unroll
    for (int i = 0; i < 4; ++i)
#pragma unroll
      for (int j = 0; j < 4; ++j)
        acc[i][j] = __builtin_amdgcn_mfma_f32_16x16x32_bf16(af[i], bfr[j], acc[i][j], 0, 0, 0);
  }

#pragma unroll
  for (int j = 0; j < 4; ++j) {
    const int n = n0 + wc * 64 + j * 16 + l15;
    const float bias = bo[n];
#pragma unroll
    for (int i = 0; i < 4; ++i)
#pragma unroll
      for (int r = 0; r < 4; ++r) {
        const int m = m0 + wr * 64 + i * 16 + lg * 4 + r;
        out[(size_t)m * 1024 + n] = acc[i][j][r] + bias;
      }
  }
}

// ---------------------------------------------------------------- launcher
extern "C" void kernel_launch(void* const* d_in, const int* in_sizes, int n_in,
                              void* d_out, int out_size, void* d_ws, size_t ws_size,
                              hipStream_t stream) {
  (void)in_sizes; (void)n_in; (void)out_size; (void)ws_size;
  const float* hs = (const float*)d_in[0];
  const int* mask = (const int*)d_in[1];
  const float* Wq = (const float*)d_in[2];
  const float* bq = (const float*)d_in[3];
  const float* Wk = (const float*)d_in[4];
  const float* bk = (const float*)d_in[5];
  const float* Wv = (const float*)d_in[6];
  const float* bv = (const float*)d_in[7];
  const float* Wo = (const float*)d_in[8];
  const float* bo = (const float*)d_in[9];
  float* out = (float*)d_out;

  uint8_t* ws = (uint8_t*)d_ws;
  u16* X  = (u16*)(ws);                          // [4096][1024] bf16   8 MiB
  u16* WT = (u16*)(ws + ((size_t)8 << 20));      // [4096][1024] bf16   8 MiB (rows 0-3071 qkv^T, 3072-4095 Wo^T)
  u16* Qb = (u16*)(ws + ((size_t)16 << 20));     // 8 MiB
  u16* Kb = (u16*)(ws + ((size_t)24 << 20));     // 8 MiB
  u16* Vb = (u16*)(ws + ((size_t)32 << 20));     // 8 MiB
  u16* AO = (u16*)(ws + ((size_t)40 << 20));     // 8 MiB
  unsigned long long* MB = (unsigned long long*)(ws + ((size_t)48 << 20));  // 512 KiB

  cvt_hs_kernel<<<dim3(4096), dim3(256), 0, stream>>>((const float4*)hs, (u16x4*)X);
  cvt_transpose_kernel<<<dim3(32, 32, 4), dim3(32, 8), 0, stream>>>(Wq, Wk, Wv, Wo, WT);
  mask_bits_kernel<<<dim3(16384), dim3(256), 0, stream>>>(mask, MB);
  gemm_qkv_kernel<<<dim3(24, 32), dim3(256), 0, stream>>>(X, WT, bq, bk, bv, Qb, Kb, Vb);
  attn_kernel<<<dim3(1024), dim3(256), 0, stream>>>(Qb, Kb, Vb, MB, AO);
  gemm_out_kernel<<<dim3(8, 32), dim3(256), 0, stream>>>(AO, WT + (size_t)3072 * 1024, bo, out);
}

// Round 2
// 206.620 us; speedup vs baseline: 1.5641x; 1.5641x over previous
//
#include <hip/hip_runtime.h>
#include <hip/hip_bf16.h>
#include <stdint.h>

typedef unsigned short u16;
typedef short short8 __attribute__((ext_vector_type(8)));
typedef float f32x4 __attribute__((ext_vector_type(4)));
typedef u16 u16x4 __attribute__((ext_vector_type(4)));

#define LOG2E 1.4426950408889634f

// fp32 -> bf16 RNE (values are finite; no NaN handling needed)
static __device__ __forceinline__ u16 f2bf(float f) {
  unsigned u = __float_as_uint(f);
  unsigned rnd = 0x7fffu + ((u >> 16) & 1u);
  return (u16)((u + rnd) >> 16);
}

static __device__ __forceinline__ void gload_lds16(const void* g, void* l) {
  __builtin_amdgcn_global_load_lds(
      (const __attribute__((address_space(1))) unsigned int*)g,
      (__attribute__((address_space(3))) unsigned int*)l, 16, 0, 0);
}

// ---------------------------------------------------------------- converts
__global__ __launch_bounds__(256) void cvt_hs_kernel(const float4* __restrict__ src,
                                                     u16x4* __restrict__ dst) {
  int i = blockIdx.x * 256 + threadIdx.x;
  float4 v = src[i];
  u16x4 o;
  o[0] = f2bf(v.x); o[1] = f2bf(v.y); o[2] = f2bf(v.z); o[3] = f2bf(v.w);
  dst[i] = o;
}

// W [1024][1024] fp32 -> WT [1024][1024] bf16 transposed
__global__ __launch_bounds__(256) void cvt_transpose_kernel(
    const float* __restrict__ Wq, const float* __restrict__ Wk,
    const float* __restrict__ Wv, const float* __restrict__ Wo,
    u16* __restrict__ WT) {
  __shared__ float tile[32][33];
  const int z = blockIdx.z;
  const float* src = (z == 0) ? Wq : (z == 1) ? Wk : (z == 2) ? Wv : Wo;
  u16* dst = WT + (size_t)z * 1024 * 1024;
  const int row0 = blockIdx.y * 32, col0 = blockIdx.x * 32;
  const int tx = threadIdx.x, ty = threadIdx.y;  // (32, 8)
#pragma unroll
  for (int i = 0; i < 4; ++i)
    tile[ty + i * 8][tx] = src[(size_t)(row0 + ty + i * 8) * 1024 + col0 + tx];
  __syncthreads();
#pragma unroll
  for (int i = 0; i < 4; ++i) {
    int r = ty + i * 8;
    dst[(size_t)(col0 + r) * 1024 + row0 + tx] = f2bf(tile[tx][r]);
  }
}

// tree_mask [2048][2048] int32 -> bits [2048][32] uint64
__global__ __launch_bounds__(256) void mask_bits_kernel(const int* __restrict__ mask,
                                                        unsigned long long* __restrict__ bits) {
  int gw = blockIdx.x * 4 + (threadIdx.x >> 6);
  int lane = threadIdx.x & 63;
  int q = gw >> 5, w = gw & 31;
  int mv = mask[(size_t)q * 2048 + w * 64 + lane];
  unsigned long long bal = __ballot(mv != 0);
  if (lane == 0) bits[(size_t)q * 32 + w] = bal;
}

// ---------------------------------------------------------------- GEMM QKV
__global__ __launch_bounds__(256) void gemm_qkv_kernel(
    const u16* __restrict__ X, const u16* __restrict__ WT,
    const float* __restrict__ bq, const float* __restrict__ bk, const float* __restrict__ bv,
    u16* __restrict__ Qb, u16* __restrict__ Kb, u16* __restrict__ Vb) {
  __shared__ u16 As[128 * 32];
  __shared__ u16 Bs[128 * 32];
  const int tid = threadIdx.x;
  const int lane = tid & 63, wid = tid >> 6;
  const int l15 = lane & 15, lg = lane >> 4;
  const int n0 = blockIdx.x * 128, m0 = blockIdx.y * 128;
  const int wr = wid >> 1, wc = wid & 1;

  f32x4 acc[4][4] = {};

  for (int kt = 0; kt < 32; ++kt) {
    __syncthreads();
#pragma unroll
    for (int p = 0; p < 2; ++p) {
      const int c = p * 256 + tid;
      const int r = c >> 2, ch = c & 3;
      gload_lds16(X + (size_t)(m0 + r) * 1024 + kt * 32 + ch * 8,
                  &As[(p * 256 + wid * 64) * 8]);
      gload_lds16(WT + (size_t)(n0 + r) * 1024 + kt * 32 + ch * 8,
                  &Bs[(p * 256 + wid * 64) * 8]);
    }
    __syncthreads();
    short8 af[4], bfr[4];
#pragma unroll
    for (int i = 0; i < 4; ++i) {
      af[i] = *reinterpret_cast<const short8*>(&As[(wr * 64 + i * 16 + l15) * 32 + lg * 8]);
      bfr[i] = *reinterpret_cast<const short8*>(&Bs[(wc * 64 + i * 16 + l15) * 32 + lg * 8]);
    }
#pragma unroll
    for (int i = 0; i < 4; ++i)
#pragma unroll
      for (int j = 0; j < 4; ++j)
        acc[i][j] = __builtin_amdgcn_mfma_f32_16x16x32_bf16(af[i], bfr[j], acc[i][j], 0, 0, 0);
  }

#pragma unroll
  for (int j = 0; j < 4; ++j) {
    const int n = n0 + wc * 64 + j * 16 + l15;
    const float bias = (n < 1024) ? bq[n] : (n < 2048) ? bk[n - 1024] : bv[n - 2048];
    u16* dst = (n < 1024) ? Qb : (n < 2048) ? Kb : Vb;
    const int nl = n & 1023;
    const int hh = nl >> 6, d = nl & 63;
#pragma unroll
    for (int i = 0; i < 4; ++i) {
#pragma unroll
      for (int r = 0; r < 4; ++r) {
        const int m = m0 + wr * 64 + i * 16 + lg * 4 + r;
        const int bb = m >> 11, t = m & 2047;
        dst[((size_t)(bb * 16 + hh) * 2048 + t) * 64 + d] = f2bf(acc[i][j][r] + bias);
      }
    }
  }
}

// ------------------------------------------------------------ V transpose
// Vb [32 bh][2048][64] -> VT [32 bh][64][2048]
__global__ __launch_bounds__(256) void transpose_v_kernel(const u16* __restrict__ Vb,
                                                          u16* __restrict__ VT) {
  __shared__ u16 tile[64][68];
  const int tid = threadIdx.x;
  const int tt = blockIdx.x & 31;
  const int bh = blockIdx.x >> 5;
  const size_t base = (size_t)bh * 2048 * 64;
  const int t0 = tt * 64;
#pragma unroll
  for (int p = 0; p < 2; ++p) {
    int i = p * 256 + tid;
    int row = i >> 3, ch = i & 7;
    *reinterpret_cast<short8*>(&tile[row][ch * 8]) =
        *reinterpret_cast<const short8*>(Vb + base + (size_t)(t0 + row) * 64 + ch * 8);
  }
  __syncthreads();
#pragma unroll
  for (int p = 0; p < 2; ++p) {
    int i = p * 256 + tid;
    int d = i >> 3, ch = i & 7;
    short8 v;
#pragma unroll
    for (int j = 0; j < 8; ++j) v[j] = tile[ch * 8 + j][d];
    *reinterpret_cast<short8*>(VT + base + (size_t)d * 2048 + t0 + ch * 8) = v;
  }
}

// ---------------------------------------------------------------- attention
// Q/K [2][16][2048][64] bf16 ; VT [2][16][64][2048] bf16 ; MB [2048][32] u64
// AO [4096][1024] bf16
__global__ __launch_bounds__(256, 4) void attn_kernel(
    const u16* __restrict__ Q, const u16* __restrict__ K, const u16* __restrict__ VT,
    const unsigned long long* __restrict__ MB, u16* __restrict__ AO) {
  // K/V tiles stored as [panel][64 rows][32 elem] so that linear gload_lds dest
  // and stride-64B fragment reads are both exactly-even across banks.
  __shared__ u16 K_lds[2][4096];
  __shared__ u16 V_lds[2][4096];
  __shared__ u16 p_lds[4][16][40];  // per-wave P staging, stride 80B (even-bank b64/b128)
  __shared__ unsigned act_lds;

  const int tid = threadIdx.x;
  const int wid = tid >> 6, lane = tid & 63;
  const int l15 = lane & 15, lg = lane >> 4;

  const int qt = blockIdx.x;
  const int h = blockIdx.y;
  const int b = blockIdx.z;
  const int qbase = qt * 64;
  const size_t bh_off = ((size_t)(b * 16 + h)) * 2048 * 64;

  // ---- per-block active-tile bitmap (one pass, replaces per-tile barrier-OR)
  if (tid == 0) act_lds = 0;
  __syncthreads();
  {
    const int ktc = tid & 31, qg = tid >> 5;
    unsigned long long orw = 0;
#pragma unroll
    for (int i = 0; i < 8; ++i)
      orw |= MB[(size_t)(qbase + qg * 8 + i) * 32 + ktc];
    if (orw) atomicOr(&act_lds, 1u << ktc);
  }

  // ---- Q fragments (B-side: lane l15 = q-row, k = d contiguous)
  const int q = qbase + wid * 16 + l15;
  const short8* qp = reinterpret_cast<const short8*>(Q + bh_off + (size_t)q * 64);
  const short8 qf0 = qp[lg];
  const short8 qf1 = qp[4 + lg];

  // ---- staging address precompute (per thread, two calls p=0,1)
  int offK[2], offV[2], ldsi[2];
#pragma unroll
  for (int p = 0; p < 2; ++p) {
    const int i = wid * 128 + p * 64 + lane;
    const int pc = i >> 8, row = (i >> 2) & 63, lgc = i & 3;
    offK[p] = row * 64 + pc * 32 + lgc * 8;    // + kt*64*64
    offV[p] = row * 2048 + pc * 32 + lgc * 8;  // + kt*64
    ldsi[p] = (wid * 128 + p * 64) * 8;        // wave-uniform u16 index
  }
  const u16* Kg = K + bh_off;
  const u16* Vg = VT + bh_off;

  __syncthreads();
  unsigned rem = act_lds;

  f32x4 O[4] = {};
  float mrow = -3e38f, lrow = 0.f;
  int buf = 0;

#define STAGE_TILE(bb, ktv)                                        \
  do {                                                             \
    const u16* ksrc_ = Kg + (ktv) * 64 * 64;                       \
    const u16* vsrc_ = Vg + (ktv) * 64;                            \
    _Pragma("unroll") for (int p_ = 0; p_ < 2; ++p_) {             \
      gload_lds16(ksrc_ + offK[p_], &K_lds[bb][ldsi[p_]]);         \
      gload_lds16(vsrc_ + offV[p_], &V_lds[bb][ldsi[p_]]);         \
    }                                                              \
  } while (0)

  if (rem) {
    int kt = __ffs(rem) - 1;
    unsigned long long w_cur = MB[(size_t)q * 32 + kt];
    STAGE_TILE(0, kt);
    __syncthreads();

    while (true) {
      rem &= rem - 1;
      int ktn = -1;
      unsigned long long w_next = 0;
      if (rem) {
        ktn = __ffs(rem) - 1;
        w_next = MB[(size_t)q * 32 + ktn];
        STAGE_TILE(buf ^ 1, ktn);
      }

      // ---- S^T = mfma(K, Q): lane l15 holds 16 k-values for its q-row
      f32x4 sT[4] = {};
#pragma unroll
      for (int dc = 0; dc < 2; ++dc) {
        const short8 qv = dc ? qf1 : qf0;
#pragma unroll
        for (int sub = 0; sub < 4; ++sub) {
          const short8 kf = *reinterpret_cast<const short8*>(
              &K_lds[buf][dc * 2048 + (sub * 16 + l15) * 32 + lg * 8]);
          sT[sub] = __builtin_amdgcn_mfma_f32_16x16x32_bf16(kf, qv, sT[sub], 0, 0, 0);
        }
      }

      // ---- mask + row-max (local 16 + 2 shfls over the lg axis)
      float pm = -1e30f;
#pragma unroll
      for (int sub = 0; sub < 4; ++sub)
#pragma unroll
        for (int r = 0; r < 4; ++r) {
          const bool bit = (w_cur >> (sub * 16 + lg * 4 + r)) & 1ull;
          const float val = bit ? sT[sub][r] * 0.125f : -1e30f;
          sT[sub][r] = val;
          pm = fmaxf(pm, val);
        }
      pm = fmaxf(pm, __shfl_xor(pm, 16));
      pm = fmaxf(pm, __shfl_xor(pm, 32));
      const float mn = fmaxf(mrow, pm);
      const float al = exp2f((mrow - mn) * LOG2E);
      mrow = mn;
      lrow *= al;
#pragma unroll
      for (int dt = 0; dt < 4; ++dt) O[dt] *= al;

      // ---- P = exp(S-mn), staged per 32-k round through per-wave LDS; PV
      float lsum = 0.f;
#pragma unroll
      for (int kc = 0; kc < 2; ++kc) {
#pragma unroll
        for (int s2 = 0; s2 < 2; ++s2) {
          const int sub = kc * 2 + s2;
          float e[4];
#pragma unroll
          for (int r = 0; r < 4; ++r) {
            const float v = sT[sub][r];
            e[r] = (v > -1e29f) ? exp2f((v - mn) * LOG2E) : 0.f;
            lsum += e[r];
          }
          uint2 pk;
          pk.x = (unsigned)f2bf(e[0]) | ((unsigned)f2bf(e[1]) << 16);
          pk.y = (unsigned)f2bf(e[2]) | ((unsigned)f2bf(e[3]) << 16);
          *reinterpret_cast<uint2*>(&p_lds[wid][l15][s2 * 16 + lg * 4]) = pk;
        }
        const short8 pf = *reinterpret_cast<const short8*>(&p_lds[wid][l15][lg * 8]);
#pragma unroll
        for (int dt = 0; dt < 4; ++dt) {
          const short8 vf = *reinterpret_cast<const short8*>(
              &V_lds[buf][kc * 2048 + (dt * 16 + l15) * 32 + lg * 8]);
          O[dt] = __builtin_amdgcn_mfma_f32_16x16x32_bf16(vf, pf, O[dt], 0, 0, 0);
        }
      }
      lsum += __shfl_xor(lsum, 16);
      lsum += __shfl_xor(lsum, 32);
      lrow += lsum;

      if (ktn < 0) break;
      __syncthreads();  // all waves done with buf; staging of buf^1 drained by barrier
      buf ^= 1;
      kt = ktn;
      w_cur = w_next;
    }
  }
#undef STAGE_TILE

  // ---- epilogue: O^T D-layout -> AO[token][h*64+d]
  const float inv = (lrow > 0.f) ? (1.0f / lrow) : 0.f;
  u16* dst = AO + ((size_t)(b * 2048 + q)) * 1024 + h * 64;
#pragma unroll
  for (int dt = 0; dt < 4; ++dt) {
    u16x4 pk;
#pragma unroll
    for (int r = 0; r < 4; ++r) pk[r] = f2bf(O[dt][r] * inv);
    *reinterpret_cast<u16x4*>(dst + dt * 16 + lg * 4) = pk;
  }
}

// ---------------------------------------------------------------- out GEMM
__global__ __launch_bounds__(256) void gemm_out_kernel(
    const u16* __restrict__ A, const u16* __restrict__ BT,
    const float* __restrict__ bo, float* __restrict__ out) {
  __shared__ u16 As[128 * 32];
  __shared__ u16 Bs[128 * 32];
  const int tid = threadIdx.x;
  const int lane = tid & 63, wid = tid >> 6;
  const int l15 = lane & 15, lg = lane >> 4;
  const int n0 = blockIdx.x * 128, m0 = blockIdx.y * 128;
  const int wr = wid >> 1, wc = wid & 1;

  f32x4 acc[4][4] = {};

  for (int kt = 0; kt < 32; ++kt) {
    __syncthreads();
#pragma unroll
    for (int p = 0; p < 2; ++p) {
      const int c = p * 256 + tid;
      const int r = c >> 2, ch = c & 3;
      gload_lds16(A + (size_t)(m0 + r) * 1024 + kt * 32 + ch * 8,
                  &As[(p * 256 + wid * 64) * 8]);
      gload_lds16(BT + (size_t)(n0 + r) * 1024 + kt * 32 + ch * 8,
                  &Bs[(p * 256 + wid * 64) * 8]);
    }
    __syncthreads();
    short8 af[4], bfr[4];
#pragma unroll
    for (int i = 0; i < 4; ++i) {
      af[i] = *reinterpret_cast<const short8*>(&As[(wr * 64 + i * 16 + l15) * 32 + lg * 8]);
      bfr[i] = *reinterpret_cast<const short8*>(&Bs[(wc * 64 + i * 16 + l15) * 32 + lg * 8]);
    }
#pragma unroll
    for (int i = 0; i < 4; ++i)
#pragma unroll
      for (int j = 0; j < 4; ++j)
        acc[i][j] = __builtin_amdgcn_mfma_f32_16x16x32_bf16(af[i], bfr[j], acc[i][j], 0, 0, 0);
  }

#pragma unroll
  for (int j = 0; j < 4; ++j) {
    const int n = n0 + wc * 64 + j * 16 + l15;
    const float bias = bo[n];
#pragma unroll
    for (int i = 0; i < 4; ++i)
#pragma unroll
      for (int r = 0; r < 4; ++r) {
        const int m = m0 + wr * 64 + i * 16 + lg * 4 + r;
        out[(size_t)m * 1024 + n] = acc[i][j][r] + bias;
      }
  }
}

// ---------------------------------------------------------------- launcher
extern "C" void kernel_launch(void* const* d_in, const int* in_sizes, int n_in,
                              void* d_out, int out_size, void* d_ws, size_t ws_size,
                              hipStream_t stream) {
  (void)in_sizes; (void)n_in; (void)out_size; (void)ws_size;
  const float* hs = (const float*)d_in[0];
  const int* mask = (const int*)d_in[1];
  const float* Wq = (const float*)d_in[2];
  const float* bq = (const float*)d_in[3];
  const float* Wk = (const float*)d_in[4];
  const float* bk = (const float*)d_in[5];
  const float* Wv = (const float*)d_in[6];
  const float* bv = (const float*)d_in[7];
  const float* Wo = (const float*)d_in[8];
  const float* bo = (const float*)d_in[9];
  float* out = (float*)d_out;

  uint8_t* ws = (uint8_t*)d_ws;
  u16* X  = (u16*)(ws);                          // [4096][1024] bf16   8 MiB (dead after gemm_qkv)
  u16* WT = (u16*)(ws + ((size_t)8 << 20));      // 8 MiB
  u16* Qb = (u16*)(ws + ((size_t)16 << 20));     // 8 MiB
  u16* Kb = (u16*)(ws + ((size_t)24 << 20));     // 8 MiB
  u16* Vb = (u16*)(ws + ((size_t)32 << 20));     // 8 MiB
  u16* AO = (u16*)(ws + ((size_t)40 << 20));     // 8 MiB
  unsigned long long* MB = (unsigned long long*)(ws + ((size_t)48 << 20));  // 512 KiB
  u16* VbT = X;                                  // reuse X region for V^T

  cvt_hs_kernel<<<dim3(4096), dim3(256), 0, stream>>>((const float4*)hs, (u16x4*)X);
  cvt_transpose_kernel<<<dim3(32, 32, 4), dim3(32, 8), 0, stream>>>(Wq, Wk, Wv, Wo, WT);
  mask_bits_kernel<<<dim3(16384), dim3(256), 0, stream>>>(mask, MB);
  gemm_qkv_kernel<<<dim3(24, 32), dim3(256), 0, stream>>>(X, WT, bq, bk, bv, Qb, Kb, Vb);
  transpose_v_kernel<<<dim3(1024), dim3(256), 0, stream>>>(Vb, VbT);
  attn_kernel<<<dim3(32, 16, 2), dim3(256), 0, stream>>>(Qb, Kb, VbT, MB, AO);
  gemm_out_kernel<<<dim3(8, 32), dim3(256), 0, stream>>>(AO, WT + (size_t)3072 * 1024, bo, out);
}

// Round 4
// 175.842 us; speedup vs baseline: 1.8379x; 1.1750x over previous
//
#include <hip/hip_runtime.h>
#include <hip/hip_bf16.h>
#include <stdint.h>

typedef unsigned short u16;
typedef short short8 __attribute__((ext_vector_type(8)));
typedef float f32x4 __attribute__((ext_vector_type(4)));
typedef u16 u16x4 __attribute__((ext_vector_type(4)));

#define LOG2E 1.4426950408889634f
#define SCLOG 0.18033688011112042f  // 0.125 * log2(e)

// fp32 -> bf16 RNE (values are finite; no NaN handling needed)
static __device__ __forceinline__ u16 f2bf(float f) {
  unsigned u = __float_as_uint(f);
  unsigned rnd = 0x7fffu + ((u >> 16) & 1u);
  return (u16)((u + rnd) >> 16);
}

// packed f32x2 -> bf16x2 via HW v_cvt_pk_bf16_f32 (no builtin on gfx950; T12/m240)
static __device__ __forceinline__ unsigned pk_bf16(float a, float b) {
  unsigned r;
  asm("v_cvt_pk_bf16_f32 %0, %1, %2" : "=v"(r) : "v"(a), "v"(b));
  return r;
}

static __device__ __forceinline__ void gload_lds16(const void* g, void* l) {
  __builtin_amdgcn_global_load_lds(
      (const __attribute__((address_space(1))) unsigned int*)g,
      (__attribute__((address_space(3))) unsigned int*)l, 16, 0, 0);
}

// ---------------------------------------------------------------- converts
__global__ __launch_bounds__(256) void cvt_hs_kernel(const float4* __restrict__ src,
                                                     u16x4* __restrict__ dst) {
  int i = blockIdx.x * 256 + threadIdx.x;
  float4 v = src[i];
  u16x4 o;
  o[0] = f2bf(v.x); o[1] = f2bf(v.y); o[2] = f2bf(v.z); o[3] = f2bf(v.w);
  dst[i] = o;
}

// W [1024][1024] fp32 -> WT [1024][1024] bf16 transposed
__global__ __launch_bounds__(256) void cvt_transpose_kernel(
    const float* __restrict__ Wq, const float* __restrict__ Wk,
    const float* __restrict__ Wv, const float* __restrict__ Wo,
    u16* __restrict__ WT) {
  __shared__ float tile[32][33];
  const int z = blockIdx.z;
  const float* src = (z == 0) ? Wq : (z == 1) ? Wk : (z == 2) ? Wv : Wo;
  u16* dst = WT + (size_t)z * 1024 * 1024;
  const int row0 = blockIdx.y * 32, col0 = blockIdx.x * 32;
  const int tx = threadIdx.x, ty = threadIdx.y;  // (32, 8)
#pragma unroll
  for (int i = 0; i < 4; ++i)
    tile[ty + i * 8][tx] = src[(size_t)(row0 + ty + i * 8) * 1024 + col0 + tx];
  __syncthreads();
#pragma unroll
  for (int i = 0; i < 4; ++i) {
    int r = ty + i * 8;
    dst[(size_t)(col0 + r) * 1024 + row0 + tx] = f2bf(tile[tx][r]);
  }
}

// tree_mask [2048][2048] int32 -> bits [2048][32] uint64
__global__ __launch_bounds__(256) void mask_bits_kernel(const int* __restrict__ mask,
                                                        unsigned long long* __restrict__ bits) {
  int gw = blockIdx.x * 4 + (threadIdx.x >> 6);
  int lane = threadIdx.x & 63;
  int q = gw >> 5, w = gw & 31;
  int mv = mask[(size_t)q * 2048 + w * 64 + lane];
  unsigned long long bal = __ballot(mv != 0);
  if (lane == 0) bits[(size_t)q * 32 + w] = bal;
}

// ---------------------------------------------------------------- GEMM QKV
__global__ __launch_bounds__(256) void gemm_qkv_kernel(
    const u16* __restrict__ X, const u16* __restrict__ WT,
    const float* __restrict__ bq, const float* __restrict__ bk, const float* __restrict__ bv,
    u16* __restrict__ Qb, u16* __restrict__ Kb, u16* __restrict__ Vb) {
  __shared__ u16 As[128 * 32];
  __shared__ u16 Bs[128 * 32];
  const int tid = threadIdx.x;
  const int lane = tid & 63, wid = tid >> 6;
  const int l15 = lane & 15, lg = lane >> 4;
  const int n0 = blockIdx.x * 128, m0 = blockIdx.y * 128;
  const int wr = wid >> 1, wc = wid & 1;

  f32x4 acc[4][4] = {};

  for (int kt = 0; kt < 32; ++kt) {
    __syncthreads();
#pragma unroll
    for (int p = 0; p < 2; ++p) {
      const int c = p * 256 + tid;
      const int r = c >> 2, ch = c & 3;
      gload_lds16(X + (size_t)(m0 + r) * 1024 + kt * 32 + ch * 8,
                  &As[(p * 256 + wid * 64) * 8]);
      gload_lds16(WT + (size_t)(n0 + r) * 1024 + kt * 32 + ch * 8,
                  &Bs[(p * 256 + wid * 64) * 8]);
    }
    __syncthreads();
    short8 af[4], bfr[4];
#pragma unroll
    for (int i = 0; i < 4; ++i) {
      af[i] = *reinterpret_cast<const short8*>(&As[(wr * 64 + i * 16 + l15) * 32 + lg * 8]);
      bfr[i] = *reinterpret_cast<const short8*>(&Bs[(wc * 64 + i * 16 + l15) * 32 + lg * 8]);
    }
#pragma unroll
    for (int i = 0; i < 4; ++i)
#pragma unroll
      for (int j = 0; j < 4; ++j)
        acc[i][j] = __builtin_amdgcn_mfma_f32_16x16x32_bf16(af[i], bfr[j], acc[i][j], 0, 0, 0);
  }

#pragma unroll
  for (int j = 0; j < 4; ++j) {
    const int n = n0 + wc * 64 + j * 16 + l15;
    const float bias = (n < 1024) ? bq[n] : (n < 2048) ? bk[n - 1024] : bv[n - 2048];
    u16* dst = (n < 1024) ? Qb : (n < 2048) ? Kb : Vb;
    const int nl = n & 1023;
    const int hh = nl >> 6, d = nl & 63;
#pragma unroll
    for (int i = 0; i < 4; ++i) {
#pragma unroll
      for (int r = 0; r < 4; ++r) {
        const int m = m0 + wr * 64 + i * 16 + lg * 4 + r;
        const int bb = m >> 11, t = m & 2047;
        dst[((size_t)(bb * 16 + hh) * 2048 + t) * 64 + d] = f2bf(acc[i][j][r] + bias);
      }
    }
  }
}

// ------------------------------------------------------------ V transpose
// Vb [32 bh][2048][64] -> VT [32 bh][64][2048]
__global__ __launch_bounds__(256) void transpose_v_kernel(const u16* __restrict__ Vb,
                                                          u16* __restrict__ VT) {
  __shared__ u16 tile[64][68];
  const int tid = threadIdx.x;
  const int tt = blockIdx.x & 31;
  const int bh = blockIdx.x >> 5;
  const size_t base = (size_t)bh * 2048 * 64;
  const int t0 = tt * 64;
#pragma unroll
  for (int p = 0; p < 2; ++p) {
    int i = p * 256 + tid;
    int row = i >> 3, ch = i & 7;
    *reinterpret_cast<short8*>(&tile[row][ch * 8]) =
        *reinterpret_cast<const short8*>(Vb + base + (size_t)(t0 + row) * 64 + ch * 8);
  }
  __syncthreads();
#pragma unroll
  for (int p = 0; p < 2; ++p) {
    int i = p * 256 + tid;
    int d = i >> 3, ch = i & 7;
    short8 v;
#pragma unroll
    for (int j = 0; j < 8; ++j) v[j] = tile[ch * 8 + j][d];
    *reinterpret_cast<short8*>(VT + base + (size_t)d * 2048 + t0 + ch * 8) = v;
  }
}

// ---------------------------------------------------------------- attention
// Q/K [2][16][2048][64] bf16 ; VT [2][16][64][2048] bf16 ; MB [2048][32] u64
// AO [4096][1024] bf16
__global__ __launch_bounds__(256, 4) void attn_kernel(
    const u16* __restrict__ Q, const u16* __restrict__ K, const u16* __restrict__ VT,
    const unsigned long long* __restrict__ MB, u16* __restrict__ AO) {
  // K/V tiles: [panel][64 rows][4 slots of 16B], slot XOR-swizzled by (row>>1)&3
  // on BOTH the gload_lds source offset and the read address (rule #21) ->
  // fragment ds_read_b128 lands 2-way-per-bank (free, m136).
  __shared__ u16 K_lds[2][4096];
  __shared__ u16 V_lds[2][4096];
  __shared__ u16 p_lds[4][16][40];  // per-wave P staging, stride 80B (2-way banks)
  __shared__ unsigned act_lds;

  const int tid = threadIdx.x;
  const int wid = tid >> 6, lane = tid & 63;
  const int l15 = lane & 15, lg = lane >> 4;

  const int qt = 31 - (int)blockIdx.x;  // heavy (causal) blocks dispatch first
  const int h = blockIdx.y;
  const int b = blockIdx.z;
  const int qbase = qt * 64;
  const size_t bh_off = ((size_t)(b * 16 + h)) * 2048 * 64;

  // ---- per-block active-tile bitmap
  if (tid == 0) act_lds = 0;
  __syncthreads();
  {
    const int ktc = tid & 31, qg = tid >> 5;
    unsigned long long orw = 0;
#pragma unroll
    for (int i = 0; i < 8; ++i)
      orw |= MB[(size_t)(qbase + qg * 8 + i) * 32 + ktc];
    if (orw) atomicOr(&act_lds, 1u << ktc);
  }

  // ---- Q fragments (B-side: lane l15 = q-row, k = d contiguous)
  const int q = qbase + wid * 16 + l15;
  const short8* qp = reinterpret_cast<const short8*>(Q + bh_off + (size_t)q * 64);
  const short8 qf0 = qp[lg];
  const short8 qf1 = qp[4 + lg];

  // swizzled fragment slot offset (u16 units): (row>>1)&3 == (l15>>1)&3 for row=sub*16+l15
  const int slg = (lg ^ ((l15 >> 1) & 3)) * 8;

  // ---- staging address precompute
  int offK[2], offV[2], ldsi[2];
#pragma unroll
  for (int p = 0; p < 2; ++p) {
    const int i = wid * 128 + p * 64 + lane;
    const int pc = i >> 8, row = (i >> 2) & 63, lgc = i & 3;
    const int lgs = lgc ^ ((i >> 3) & 3);      // slot ^ ((row>>1)&3)
    offK[p] = row * 64 + pc * 32 + lgs * 8;    // + kt*64*64
    offV[p] = row * 2048 + pc * 32 + lgs * 8;  // + kt*64
    ldsi[p] = (wid * 128 + p * 64) * 8;        // wave-uniform u16 index (linear dest)
  }
  const u16* Kg = K + bh_off;
  const u16* Vg = VT + bh_off;

  __syncthreads();
  unsigned rem = act_lds;

  f32x4 O[4] = {};
  float mrow = -3e38f, lrow = 0.f;
  int buf = 0;

#define STAGE_TILE(bb, ktv)                                        \
  do {                                                             \
    const u16* ksrc_ = Kg + (ktv) * 64 * 64;                       \
    const u16* vsrc_ = Vg + (ktv) * 64;                            \
    _Pragma("unroll") for (int p_ = 0; p_ < 2; ++p_) {             \
      gload_lds16(ksrc_ + offK[p_], &K_lds[bb][ldsi[p_]]);         \
      gload_lds16(vsrc_ + offV[p_], &V_lds[bb][ldsi[p_]]);         \
    }                                                              \
  } while (0)

  if (rem) {
    int kt = __ffs(rem) - 1;
    unsigned long long w_cur = MB[(size_t)q * 32 + kt];
    STAGE_TILE(0, kt);
    __syncthreads();

    while (true) {
      rem &= rem - 1;
      int ktn = -1;
      unsigned long long w_next = 0;
      if (rem) {
        ktn = __ffs(rem) - 1;
        w_next = MB[(size_t)q * 32 + ktn];
        STAGE_TILE(buf ^ 1, ktn);
      }

      // ---- S^T = mfma(K, Q): lane l15 holds 16 k-values for its q-row
      f32x4 sT[4] = {};
#pragma unroll
      for (int dc = 0; dc < 2; ++dc) {
        const short8 qv = dc ? qf1 : qf0;
#pragma unroll
        for (int sub = 0; sub < 4; ++sub) {
          const short8 kf = *reinterpret_cast<const short8*>(
              &K_lds[buf][dc * 2048 + (sub * 16 + l15) * 32 + slg]);
          sT[sub] = __builtin_amdgcn_mfma_f32_16x16x32_bf16(kf, qv, sT[sub], 0, 0, 0);
        }
      }

      // ---- scale into log2 domain + mask; full-tile fast path skips mask VALU
      float pm = -3e38f;
      if (__all(w_cur == ~0ull)) {
#pragma unroll
        for (int sub = 0; sub < 4; ++sub)
#pragma unroll
          for (int r = 0; r < 4; ++r) {
            const float val = sT[sub][r] * SCLOG;
            sT[sub][r] = val;
            pm = fmaxf(pm, val);
          }
      } else {
        const unsigned mlo = (unsigned)w_cur, mhi = (unsigned)(w_cur >> 32);
#pragma unroll
        for (int sub = 0; sub < 4; ++sub) {
          const unsigned f = ((sub & 2) ? mhi : mlo) >> ((sub & 1) * 16 + lg * 4);
#pragma unroll
          for (int r = 0; r < 4; ++r) {
            const float val = ((f >> r) & 1u) ? sT[sub][r] * SCLOG : -1e30f;
            sT[sub][r] = val;
            pm = fmaxf(pm, val);
          }
        }
      }
      pm = fmaxf(pm, __shfl_xor(pm, 16));
      pm = fmaxf(pm, __shfl_xor(pm, 32));
      // ---- defer-max (T13, THR=8): rescale only when the max really grows
      if (!__all(pm - mrow <= 8.f)) {
        const float mn = fmaxf(mrow, pm);
        const float al = exp2f(mrow - mn);
        mrow = mn;
        lrow *= al;
#pragma unroll
        for (int dt = 0; dt < 4; ++dt) O[dt] *= al;
      }

      // ---- P = exp2(S - m), pack via v_cvt_pk_bf16_f32, stage, PV
      float lsum = 0.f;
#pragma unroll
      for (int kc = 0; kc < 2; ++kc) {
#pragma unroll
        for (int s2 = 0; s2 < 2; ++s2) {
          const int sub = kc * 2 + s2;
          const float e0 = exp2f(sT[sub][0] - mrow);
          const float e1 = exp2f(sT[sub][1] - mrow);
          const float e2 = exp2f(sT[sub][2] - mrow);
          const float e3 = exp2f(sT[sub][3] - mrow);
          lsum += (e0 + e1) + (e2 + e3);
          uint2 pk;
          pk.x = pk_bf16(e0, e1);
          pk.y = pk_bf16(e2, e3);
          *reinterpret_cast<uint2*>(&p_lds[wid][l15][s2 * 16 + lg * 4]) = pk;
        }
        const short8 pf = *reinterpret_cast<const short8*>(&p_lds[wid][l15][lg * 8]);
#pragma unroll
        for (int dt = 0; dt < 4; ++dt) {
          const short8 vf = *reinterpret_cast<const short8*>(
              &V_lds[buf][kc * 2048 + (dt * 16 + l15) * 32 + slg]);
          O[dt] = __builtin_amdgcn_mfma_f32_16x16x32_bf16(vf, pf, O[dt], 0, 0, 0);
        }
      }
      lsum += __shfl_xor(lsum, 16);
      lsum += __shfl_xor(lsum, 32);
      lrow += lsum;

      if (ktn < 0) break;
      __syncthreads();  // all waves done with buf; prefetch of buf^1 drained
      buf ^= 1;
      kt = ktn;
      w_cur = w_next;
    }
  }
#undef STAGE_TILE

  // ---- epilogue: O^T D-layout -> AO[token][h*64+d]
  const float inv = (lrow > 0.f) ? (1.0f / lrow) : 0.f;
  u16* dst = AO + ((size_t)(b * 2048 + q)) * 1024 + h * 64;
#pragma unroll
  for (int dt = 0; dt < 4; ++dt) {
    uint2 pk;
    pk.x = pk_bf16(O[dt][0] * inv, O[dt][1] * inv);
    pk.y = pk_bf16(O[dt][2] * inv, O[dt][3] * inv);
    *reinterpret_cast<uint2*>(dst + dt * 16 + lg * 4) = pk;
  }
}

// ---------------------------------------------------------------- out GEMM
__global__ __launch_bounds__(256) void gemm_out_kernel(
    const u16* __restrict__ A, const u16* __restrict__ BT,
    const float* __restrict__ bo, float* __restrict__ out) {
  __shared__ u16 As[128 * 32];
  __shared__ u16 Bs[128 * 32];
  const int tid = threadIdx.x;
  const int lane = tid & 63, wid = tid >> 6;
  const int l15 = lane & 15, lg = lane >> 4;
  const int n0 = blockIdx.x * 128, m0 = blockIdx.y * 128;
  const int wr = wid >> 1, wc = wid & 1;

  f32x4 acc[4][4] = {};

  for (int kt = 0; kt < 32; ++kt) {
    __syncthreads();
#pragma unroll
    for (int p = 0; p < 2; ++p) {
      const int c = p * 256 + tid;
      const int r = c >> 2, ch = c & 3;
      gload_lds16(A + (size_t)(m0 + r) * 1024 + kt * 32 + ch * 8,
                  &As[(p * 256 + wid * 64) * 8]);
      gload_lds16(BT + (size_t)(n0 + r) * 1024 + kt * 32 + ch * 8,
                  &Bs[(p * 256 + wid * 64) * 8]);
    }
    __syncthreads();
    short8 af[4], bfr[4];
#pragma unroll
    for (int i = 0; i < 4; ++i) {
      af[i] = *reinterpret_cast<const short8*>(&As[(wr * 64 + i * 16 + l15) * 32 + lg * 8]);
      bfr[i] = *reinterpret_cast<const short8*>(&Bs[(wc * 64 + i * 16 + l15) * 32 + lg * 8]);
    }
#pragma unroll
    for (int i = 0; i < 4; ++i)
#pragma unroll
      for (int j = 0; j < 4; ++j)
        acc[i][j] = __builtin_amdgcn_mfma_f32_16x16x32_bf16(af[i], bfr[j], acc[i][j], 0, 0, 0);
  }

#pragma unroll
  for (int j = 0; j < 4; ++j) {
    const int n = n0 + wc * 64 + j * 16 + l15;
    const float bias = bo[n];
#pragma unroll
    for (int i = 0; i < 4; ++i)
#pragma unroll
      for (int r = 0; r < 4; ++r) {
        const int m = m0 + wr * 64 + i * 16 + lg * 4 + r;
        out[(size_t)m * 1024 + n] = acc[i][j][r] + bias;
      }
  }
}

// ---------------------------------------------------------------- launcher
extern "C" void kernel_launch(void* const* d_in, const int* in_sizes, int n_in,
                              void* d_out, int out_size, void* d_ws, size_t ws_size,
                              hipStream_t stream) {
  (void)in_sizes; (void)n_in; (void)out_size; (void)ws_size;
  const float* hs = (const float*)d_in[0];
  const int* mask = (const int*)d_in[1];
  const float* Wq = (const float*)d_in[2];
  const float* bq = (const float*)d_in[3];
  const float* Wk = (const float*)d_in[4];
  const float* bk = (const float*)d_in[5];
  const float* Wv = (const float*)d_in[6];
  const float* bv = (const float*)d_in[7];
  const float* Wo = (const float*)d_in[8];
  const float* bo = (const float*)d_in[9];
  float* out = (float*)d_out;

  uint8_t* ws = (uint8_t*)d_ws;
  u16* X  = (u16*)(ws);                          // 8 MiB (dead after gemm_qkv)
  u16* WT = (u16*)(ws + ((size_t)8 << 20));      // 8 MiB
  u16* Qb = (u16*)(ws + ((size_t)16 << 20));     // 8 MiB
  u16* Kb = (u16*)(ws + ((size_t)24 << 20));     // 8 MiB
  u16* Vb = (u16*)(ws + ((size_t)32 << 20));     // 8 MiB
  u16* AO = (u16*)(ws + ((size_t)40 << 20));     // 8 MiB
  unsigned long long* MB = (unsigned long long*)(ws + ((size_t)48 << 20));  // 512 KiB
  u16* VbT = X;                                  // reuse X region for V^T

  cvt_hs_kernel<<<dim3(4096), dim3(256), 0, stream>>>((const float4*)hs, (u16x4*)X);
  cvt_transpose_kernel<<<dim3(32, 32, 4), dim3(32, 8), 0, stream>>>(Wq, Wk, Wv, Wo, WT);
  mask_bits_kernel<<<dim3(16384), dim3(256), 0, stream>>>(mask, MB);
  gemm_qkv_kernel<<<dim3(24, 32), dim3(256), 0, stream>>>(X, WT, bq, bk, bv, Qb, Kb, Vb);
  transpose_v_kernel<<<dim3(1024), dim3(256), 0, stream>>>(Vb, VbT);
  attn_kernel<<<dim3(32, 16, 2), dim3(256), 0, stream>>>(Qb, Kb, VbT, MB, AO);
  gemm_out_kernel<<<dim3(8, 32), dim3(256), 0, stream>>>(AO, WT + (size_t)3072 * 1024, bo, out);
}

// Round 5
// 159.162 us; speedup vs baseline: 2.0305x; 1.1048x over previous
//
#include <hip/hip_runtime.h>
#include <hip/hip_bf16.h>
#include <stdint.h>

typedef unsigned short u16;
typedef short short8 __attribute__((ext_vector_type(8)));
typedef float f32x4 __attribute__((ext_vector_type(4)));
typedef u16 u16x4 __attribute__((ext_vector_type(4)));

#define SCLOG 0.18033688011112042f  // 0.125 * log2(e)

// fp32 -> bf16 RNE (values are finite; no NaN handling needed)
static __device__ __forceinline__ u16 f2bf(float f) {
  unsigned u = __float_as_uint(f);
  unsigned rnd = 0x7fffu + ((u >> 16) & 1u);
  return (u16)((u + rnd) >> 16);
}

// packed f32x2 -> bf16x2 via HW v_cvt_pk_bf16_f32 (no builtin on gfx950; T12/m240)
static __device__ __forceinline__ unsigned pk_bf16(float a, float b) {
  unsigned r;
  asm("v_cvt_pk_bf16_f32 %0, %1, %2" : "=v"(r) : "v"(a), "v"(b));
  return r;
}

static __device__ __forceinline__ void gload_lds16(const void* g, void* l) {
  __builtin_amdgcn_global_load_lds(
      (const __attribute__((address_space(1))) unsigned int*)g,
      (__attribute__((address_space(3))) unsigned int*)l, 16, 0, 0);
}

// ---------------------------------------------------------------- converts
__global__ __launch_bounds__(256) void cvt_hs_kernel(const float4* __restrict__ src,
                                                     u16x4* __restrict__ dst) {
  int i = blockIdx.x * 256 + threadIdx.x;
  float4 v = src[i];
  u16x4 o;
  o[0] = f2bf(v.x); o[1] = f2bf(v.y); o[2] = f2bf(v.z); o[3] = f2bf(v.w);
  dst[i] = o;
}

// W [1024][1024] fp32 -> WT [1024][1024] bf16 transposed
__global__ __launch_bounds__(256) void cvt_transpose_kernel(
    const float* __restrict__ Wq, const float* __restrict__ Wk,
    const float* __restrict__ Wv, const float* __restrict__ Wo,
    u16* __restrict__ WT) {
  __shared__ float tile[32][33];
  const int z = blockIdx.z;
  const float* src = (z == 0) ? Wq : (z == 1) ? Wk : (z == 2) ? Wv : Wo;
  u16* dst = WT + (size_t)z * 1024 * 1024;
  const int row0 = blockIdx.y * 32, col0 = blockIdx.x * 32;
  const int tx = threadIdx.x, ty = threadIdx.y;  // (32, 8)
#pragma unroll
  for (int i = 0; i < 4; ++i)
    tile[ty + i * 8][tx] = src[(size_t)(row0 + ty + i * 8) * 1024 + col0 + tx];
  __syncthreads();
#pragma unroll
  for (int i = 0; i < 4; ++i) {
    int r = ty + i * 8;
    dst[(size_t)(col0 + r) * 1024 + row0 + tx] = f2bf(tile[tx][r]);
  }
}

// tree_mask [2048][2048] int32 -> bits [2048][32] uint64
__global__ __launch_bounds__(256) void mask_bits_kernel(const int* __restrict__ mask,
                                                        unsigned long long* __restrict__ bits) {
  int gw = blockIdx.x * 4 + (threadIdx.x >> 6);
  int lane = threadIdx.x & 63;
  int q = gw >> 5, w = gw & 31;
  int mv = mask[(size_t)q * 2048 + w * 64 + lane];
  unsigned long long bal = __ballot(mv != 0);
  if (lane == 0) bits[(size_t)q * 32 + w] = bal;
}

// ---------------------------------------------------------------- GEMM QKV
// Q rows are pre-scaled by SCLOG so attention S arrives in exp2 domain.
__global__ __launch_bounds__(256) void gemm_qkv_kernel(
    const u16* __restrict__ X, const u16* __restrict__ WT,
    const float* __restrict__ bq, const float* __restrict__ bk, const float* __restrict__ bv,
    u16* __restrict__ Qb, u16* __restrict__ Kb, u16* __restrict__ Vb) {
  __shared__ u16 As[128 * 32];
  __shared__ u16 Bs[128 * 32];
  const int tid = threadIdx.x;
  const int lane = tid & 63, wid = tid >> 6;
  const int l15 = lane & 15, lg = lane >> 4;
  const int n0 = blockIdx.x * 128, m0 = blockIdx.y * 128;
  const int wr = wid >> 1, wc = wid & 1;

  f32x4 acc[4][4] = {};

  for (int kt = 0; kt < 32; ++kt) {
    __syncthreads();
#pragma unroll
    for (int p = 0; p < 2; ++p) {
      const int c = p * 256 + tid;
      const int r = c >> 2, ch = c & 3;
      gload_lds16(X + (size_t)(m0 + r) * 1024 + kt * 32 + ch * 8,
                  &As[(p * 256 + wid * 64) * 8]);
      gload_lds16(WT + (size_t)(n0 + r) * 1024 + kt * 32 + ch * 8,
                  &Bs[(p * 256 + wid * 64) * 8]);
    }
    __syncthreads();
    short8 af[4], bfr[4];
#pragma unroll
    for (int i = 0; i < 4; ++i) {
      af[i] = *reinterpret_cast<const short8*>(&As[(wr * 64 + i * 16 + l15) * 32 + lg * 8]);
      bfr[i] = *reinterpret_cast<const short8*>(&Bs[(wc * 64 + i * 16 + l15) * 32 + lg * 8]);
    }
#pragma unroll
    for (int i = 0; i < 4; ++i)
#pragma unroll
      for (int j = 0; j < 4; ++j)
        acc[i][j] = __builtin_amdgcn_mfma_f32_16x16x32_bf16(af[i], bfr[j], acc[i][j], 0, 0, 0);
  }

#pragma unroll
  for (int j = 0; j < 4; ++j) {
    const int n = n0 + wc * 64 + j * 16 + l15;
    const float bias = (n < 1024) ? bq[n] : (n < 2048) ? bk[n - 1024] : bv[n - 2048];
    const float scl = (n < 1024) ? SCLOG : 1.0f;
    u16* dst = (n < 1024) ? Qb : (n < 2048) ? Kb : Vb;
    const int nl = n & 1023;
    const int hh = nl >> 6, d = nl & 63;
#pragma unroll
    for (int i = 0; i < 4; ++i) {
#pragma unroll
      for (int r = 0; r < 4; ++r) {
        const int m = m0 + wr * 64 + i * 16 + lg * 4 + r;
        const int bb = m >> 11, t = m & 2047;
        dst[((size_t)(bb * 16 + hh) * 2048 + t) * 64 + d] = f2bf((acc[i][j][r] + bias) * scl);
      }
    }
  }
}

// ------------------------------------------------------------ V transpose
// Vb [32 bh][2048][64] -> VT [32 bh][64][2048]
__global__ __launch_bounds__(256) void transpose_v_kernel(const u16* __restrict__ Vb,
                                                          u16* __restrict__ VT) {
  __shared__ u16 tile[64][68];
  const int tid = threadIdx.x;
  const int tt = blockIdx.x & 31;
  const int bh = blockIdx.x >> 5;
  const size_t base = (size_t)bh * 2048 * 64;
  const int t0 = tt * 64;
#pragma unroll
  for (int p = 0; p < 2; ++p) {
    int i = p * 256 + tid;
    int row = i >> 3, ch = i & 7;
    *reinterpret_cast<short8*>(&tile[row][ch * 8]) =
        *reinterpret_cast<const short8*>(Vb + base + (size_t)(t0 + row) * 64 + ch * 8);
  }
  __syncthreads();
#pragma unroll
  for (int p = 0; p < 2; ++p) {
    int i = p * 256 + tid;
    int d = i >> 3, ch = i & 7;
    short8 v;
#pragma unroll
    for (int j = 0; j < 8; ++j) v[j] = tile[ch * 8 + j][d];
    *reinterpret_cast<short8*>(VT + base + (size_t)d * 2048 + t0 + ch * 8) = v;
  }
}

// ---------------------------------------------------------------- attention
struct AttnState {
  f32x4 O[4];
  float m, l;
  short8 qf0, qf1;
};

// one 64-k tile for one q-sub-tile state (Q pre-scaled: S already in exp2 domain)
static __device__ __forceinline__ void attn_tile(
    AttnState& st, const u16* __restrict__ Kb_, const u16* __restrict__ Vb_,
    u16* __restrict__ pwave, unsigned long long w,
    int l15, int lg, int slg) {
  f32x4 sT[4] = {};
  __builtin_amdgcn_s_setprio(1);
#pragma unroll
  for (int dc = 0; dc < 2; ++dc) {
    const short8 qv = dc ? st.qf1 : st.qf0;
#pragma unroll
    for (int sub = 0; sub < 4; ++sub) {
      const short8 kf = *reinterpret_cast<const short8*>(
          &Kb_[dc * 2048 + (sub * 16 + l15) * 32 + slg]);
      sT[sub] = __builtin_amdgcn_mfma_f32_16x16x32_bf16(kf, qv, sT[sub], 0, 0, 0);
    }
  }
  __builtin_amdgcn_s_setprio(0);

  float pm = -3e38f;
  if (__all(w == ~0ull)) {
#pragma unroll
    for (int sub = 0; sub < 4; ++sub)
#pragma unroll
      for (int r = 0; r < 4; ++r) pm = fmaxf(pm, sT[sub][r]);
  } else {
    const unsigned mlo = (unsigned)w, mhi = (unsigned)(w >> 32);
#pragma unroll
    for (int sub = 0; sub < 4; ++sub) {
      const unsigned f = ((sub & 2) ? mhi : mlo) >> ((sub & 1) * 16 + lg * 4);
#pragma unroll
      for (int r = 0; r < 4; ++r) {
        const float val = ((f >> r) & 1u) ? sT[sub][r] : -1e30f;
        sT[sub][r] = val;
        pm = fmaxf(pm, val);
      }
    }
  }
  pm = fmaxf(pm, __shfl_xor(pm, 16));
  pm = fmaxf(pm, __shfl_xor(pm, 32));
  // defer-max (T13, THR=8 in log2 units)
  if (!__all(pm - st.m <= 8.f)) {
    const float mn = fmaxf(st.m, pm);
    const float al = exp2f(st.m - mn);
    st.m = mn;
    st.l *= al;
#pragma unroll
    for (int dt = 0; dt < 4; ++dt) st.O[dt] *= al;
  }

  float lsum = 0.f;
#pragma unroll
  for (int kc = 0; kc < 2; ++kc) {
#pragma unroll
    for (int s2 = 0; s2 < 2; ++s2) {
      const int sub = kc * 2 + s2;
      const float e0 = exp2f(sT[sub][0] - st.m);
      const float e1 = exp2f(sT[sub][1] - st.m);
      const float e2 = exp2f(sT[sub][2] - st.m);
      const float e3 = exp2f(sT[sub][3] - st.m);
      lsum += (e0 + e1) + (e2 + e3);
      uint2 pk;
      pk.x = pk_bf16(e0, e1);
      pk.y = pk_bf16(e2, e3);
      *reinterpret_cast<uint2*>(&pwave[l15 * 40 + s2 * 16 + lg * 4]) = pk;
    }
    const short8 pf = *reinterpret_cast<const short8*>(&pwave[l15 * 40 + lg * 8]);
    __builtin_amdgcn_s_setprio(1);
#pragma unroll
    for (int dt = 0; dt < 4; ++dt) {
      const short8 vf = *reinterpret_cast<const short8*>(
          &Vb_[kc * 2048 + (dt * 16 + l15) * 32 + slg]);
      st.O[dt] = __builtin_amdgcn_mfma_f32_16x16x32_bf16(vf, pf, st.O[dt], 0, 0, 0);
    }
    __builtin_amdgcn_s_setprio(0);
  }
  lsum += __shfl_xor(lsum, 16);
  lsum += __shfl_xor(lsum, 32);
  st.l += lsum;
}

// Q/K [2][16][2048][64] bf16 ; VT [2][16][64][2048] bf16 ; MB [2048][32] u64
// AO [4096][1024] bf16.  Block = (pair, h, b): q-tiles qp and 31-qp share staging.
__global__ __launch_bounds__(256, 4) void attn_kernel(
    const u16* __restrict__ Q, const u16* __restrict__ K, const u16* __restrict__ VT,
    const unsigned long long* __restrict__ MB, u16* __restrict__ AO) {
  __shared__ u16 K_lds[2][4096];
  __shared__ u16 V_lds[2][4096];
  __shared__ u16 p_lds[4][16][40];
  __shared__ unsigned actA_s, actB_s;

  const int tid = threadIdx.x;
  const int wid = tid >> 6, lane = tid & 63;
  const int l15 = lane & 15, lg = lane >> 4;

  const int qp = blockIdx.x;          // 0..15
  const int qA_t = qp, qB_t = 31 - qp;
  const int h = blockIdx.y;
  const int b = blockIdx.z;
  const size_t bh_off = ((size_t)(b * 16 + h)) * 2048 * 64;

  if (tid == 0) { actA_s = 0; actB_s = 0; }
  __syncthreads();
  {
    const int ktc = tid & 31, qg = tid >> 5;
    unsigned long long orA = 0, orB = 0;
#pragma unroll
    for (int i = 0; i < 8; ++i) {
      orA |= MB[(size_t)(qA_t * 64 + qg * 8 + i) * 32 + ktc];
      orB |= MB[(size_t)(qB_t * 64 + qg * 8 + i) * 32 + ktc];
    }
    if (orA) atomicOr(&actA_s, 1u << ktc);
    if (orB) atomicOr(&actB_s, 1u << ktc);
  }

  // per-wave q rows for the two sub-tiles
  const int qa = qA_t * 64 + wid * 16 + l15;
  const int qb = qB_t * 64 + wid * 16 + l15;

  AttnState stA, stB;
  {
    const short8* qpA = reinterpret_cast<const short8*>(Q + bh_off + (size_t)qa * 64);
    const short8* qpB = reinterpret_cast<const short8*>(Q + bh_off + (size_t)qb * 64);
    stA.qf0 = qpA[lg]; stA.qf1 = qpA[4 + lg];
    stB.qf0 = qpB[lg]; stB.qf1 = qpB[4 + lg];
#pragma unroll
    for (int dt = 0; dt < 4; ++dt) { stA.O[dt] = f32x4{}; stB.O[dt] = f32x4{}; }
    stA.m = -3e38f; stA.l = 0.f;
    stB.m = -3e38f; stB.l = 0.f;
  }

  // swizzled fragment slot offset (u16 units)
  const int slg = (lg ^ ((l15 >> 1) & 3)) * 8;

  // staging address precompute
  int offK[2], offV[2], ldsi[2];
#pragma unroll
  for (int p = 0; p < 2; ++p) {
    const int i = wid * 128 + p * 64 + lane;
    const int pc = i >> 8, row = (i >> 2) & 63, lgc = i & 3;
    const int lgs = lgc ^ ((i >> 3) & 3);
    offK[p] = row * 64 + pc * 32 + lgs * 8;
    offV[p] = row * 2048 + pc * 32 + lgs * 8;
    ldsi[p] = (wid * 128 + p * 64) * 8;
  }
  const u16* Kg = K + bh_off;
  const u16* Vg = VT + bh_off;
  u16* pwave = &p_lds[wid][0][0];

  __syncthreads();
  const unsigned actA = actA_s, actB = actB_s;
  unsigned rem = actA | actB;
  int buf = 0;

#define STAGE_TILE(bb, ktv)                                        \
  do {                                                             \
    const u16* ksrc_ = Kg + (ktv) * 64 * 64;                       \
    const u16* vsrc_ = Vg + (ktv) * 64;                            \
    _Pragma("unroll") for (int p_ = 0; p_ < 2; ++p_) {             \
      gload_lds16(ksrc_ + offK[p_], &K_lds[bb][ldsi[p_]]);         \
      gload_lds16(vsrc_ + offV[p_], &V_lds[bb][ldsi[p_]]);         \
    }                                                              \
  } while (0)

  if (rem) {
    int kt = __ffs(rem) - 1;
    unsigned long long wA_cur = MB[(size_t)qa * 32 + kt];
    unsigned long long wB_cur = MB[(size_t)qb * 32 + kt];
    STAGE_TILE(0, kt);
    __syncthreads();

    while (true) {
      rem &= rem - 1;
      int ktn = -1;
      unsigned long long wA_next = 0, wB_next = 0;
      if (rem) {
        ktn = __ffs(rem) - 1;
        wA_next = MB[(size_t)qa * 32 + ktn];
        wB_next = MB[(size_t)qb * 32 + ktn];
        STAGE_TILE(buf ^ 1, ktn);
      }

      if ((actB >> kt) & 1u)
        attn_tile(stB, &K_lds[buf][0], &V_lds[buf][0], pwave, wB_cur, l15, lg, slg);
      if ((actA >> kt) & 1u)
        attn_tile(stA, &K_lds[buf][0], &V_lds[buf][0], pwave, wA_cur, l15, lg, slg);

      if (ktn < 0) break;
      __syncthreads();
      buf ^= 1;
      kt = ktn;
      wA_cur = wA_next;
      wB_cur = wB_next;
    }
  }
#undef STAGE_TILE

  // epilogue for both states
  {
    const float invA = (stA.l > 0.f) ? (1.0f / stA.l) : 0.f;
    u16* dstA = AO + ((size_t)(b * 2048 + qa)) * 1024 + h * 64;
#pragma unroll
    for (int dt = 0; dt < 4; ++dt) {
      uint2 pk;
      pk.x = pk_bf16(stA.O[dt][0] * invA, stA.O[dt][1] * invA);
      pk.y = pk_bf16(stA.O[dt][2] * invA, stA.O[dt][3] * invA);
      *reinterpret_cast<uint2*>(dstA + dt * 16 + lg * 4) = pk;
    }
    const float invB = (stB.l > 0.f) ? (1.0f / stB.l) : 0.f;
    u16* dstB = AO + ((size_t)(b * 2048 + qb)) * 1024 + h * 64;
#pragma unroll
    for (int dt = 0; dt < 4; ++dt) {
      uint2 pk;
      pk.x = pk_bf16(stB.O[dt][0] * invB, stB.O[dt][1] * invB);
      pk.y = pk_bf16(stB.O[dt][2] * invB, stB.O[dt][3] * invB);
      *reinterpret_cast<uint2*>(dstB + dt * 16 + lg * 4) = pk;
    }
  }
}

// ---------------------------------------------------------------- out GEMM
__global__ __launch_bounds__(256) void gemm_out_kernel(
    const u16* __restrict__ A, const u16* __restrict__ BT,
    const float* __restrict__ bo, float* __restrict__ out) {
  __shared__ u16 As[128 * 32];
  __shared__ u16 Bs[128 * 32];
  const int tid = threadIdx.x;
  const int lane = tid & 63, wid = tid >> 6;
  const int l15 = lane & 15, lg = lane >> 4;
  const int n0 = blockIdx.x * 128, m0 = blockIdx.y * 128;
  const int wr = wid >> 1, wc = wid & 1;

  f32x4 acc[4][4] = {};

  for (int kt = 0; kt < 32; ++kt) {
    __syncthreads();
#pragma unroll
    for (int p = 0; p < 2; ++p) {
      const int c = p * 256 + tid;
      const int r = c >> 2, ch = c & 3;
      gload_lds16(A + (size_t)(m0 + r) * 1024 + kt * 32 + ch * 8,
                  &As[(p * 256 + wid * 64) * 8]);
      gload_lds16(BT + (size_t)(n0 + r) * 1024 + kt * 32 + ch * 8,
                  &Bs[(p * 256 + wid * 64) * 8]);
    }
    __syncthreads();
    short8 af[4], bfr[4];
#pragma unroll
    for (int i = 0; i < 4; ++i) {
      af[i] = *reinterpret_cast<const short8*>(&As[(wr * 64 + i * 16 + l15) * 32 + lg * 8]);
      bfr[i] = *reinterpret_cast<const short8*>(&Bs[(wc * 64 + i * 16 + l15) * 32 + lg * 8]);
    }
#pragma unroll
    for (int i = 0; i < 4; ++i)
#pragma unroll
      for (int j = 0; j < 4; ++j)
        acc[i][j] = __builtin_amdgcn_mfma_f32_16x16x32_bf16(af[i], bfr[j], acc[i][j], 0, 0, 0);
  }

#pragma unroll
  for (int j = 0; j < 4; ++j) {
    const int n = n0 + wc * 64 + j * 16 + l15;
    const float bias = bo[n];
#pragma unroll
    for (int i = 0; i < 4; ++i)
#pragma unroll
      for (int r = 0; r < 4; ++r) {
        const int m = m0 + wr * 64 + i * 16 + lg * 4 + r;
        out[(size_t)m * 1024 + n] = acc[i][j][r] + bias;
      }
  }
}

// ---------------------------------------------------------------- launcher
extern "C" void kernel_launch(void* const* d_in, const int* in_sizes, int n_in,
                              void* d_out, int out_size, void* d_ws, size_t ws_size,
                              hipStream_t stream) {
  (void)in_sizes; (void)n_in; (void)out_size; (void)ws_size;
  const float* hs = (const float*)d_in[0];
  const int* mask = (const int*)d_in[1];
  const float* Wq = (const float*)d_in[2];
  const float* bq = (const float*)d_in[3];
  const float* Wk = (const float*)d_in[4];
  const float* bk = (const float*)d_in[5];
  const float* Wv = (const float*)d_in[6];
  const float* bv = (const float*)d_in[7];
  const float* Wo = (const float*)d_in[8];
  const float* bo = (const float*)d_in[9];
  float* out = (float*)d_out;

  uint8_t* ws = (uint8_t*)d_ws;
  u16* X  = (u16*)(ws);                          // 8 MiB (dead after gemm_qkv)
  u16* WT = (u16*)(ws + ((size_t)8 << 20));      // 8 MiB
  u16* Qb = (u16*)(ws + ((size_t)16 << 20));     // 8 MiB
  u16* Kb = (u16*)(ws + ((size_t)24 << 20));     // 8 MiB
  u16* Vb = (u16*)(ws + ((size_t)32 << 20));     // 8 MiB
  u16* AO = (u16*)(ws + ((size_t)40 << 20));     // 8 MiB
  unsigned long long* MB = (unsigned long long*)(ws + ((size_t)48 << 20));  // 512 KiB
  u16* VbT = X;                                  // reuse X region for V^T

  cvt_hs_kernel<<<dim3(4096), dim3(256), 0, stream>>>((const float4*)hs, (u16x4*)X);
  cvt_transpose_kernel<<<dim3(32, 32, 4), dim3(32, 8), 0, stream>>>(Wq, Wk, Wv, Wo, WT);
  mask_bits_kernel<<<dim3(16384), dim3(256), 0, stream>>>(mask, MB);
  gemm_qkv_kernel<<<dim3(24, 32), dim3(256), 0, stream>>>(X, WT, bq, bk, bv, Qb, Kb, Vb);
  transpose_v_kernel<<<dim3(1024), dim3(256), 0, stream>>>(Vb, VbT);
  attn_kernel<<<dim3(16, 16, 2), dim3(256), 0, stream>>>(Qb, Kb, VbT, MB, AO);
  gemm_out_kernel<<<dim3(8, 32), dim3(256), 0, stream>>>(AO, WT + (size_t)3072 * 1024, bo, out);
}

// Round 6
// 146.920 us; speedup vs baseline: 2.1997x; 1.0833x over previous
//
#include <hip/hip_runtime.h>
#include <hip/hip_bf16.h>
#include <stdint.h>

typedef unsigned short u16;
typedef short short8 __attribute__((ext_vector_type(8)));
typedef float f32x4 __attribute__((ext_vector_type(4)));
typedef u16 u16x4 __attribute__((ext_vector_type(4)));

#define SCLOG 0.18033688011112042f  // 0.125 * log2(e)

// fp32 -> bf16 RNE (values are finite; no NaN handling needed)
static __device__ __forceinline__ u16 f2bf(float f) {
  unsigned u = __float_as_uint(f);
  unsigned rnd = 0x7fffu + ((u >> 16) & 1u);
  return (u16)((u + rnd) >> 16);
}

// packed f32x2 -> bf16x2 via HW v_cvt_pk_bf16_f32 (no builtin on gfx950; T12/m240)
static __device__ __forceinline__ unsigned pk_bf16(float a, float b) {
  unsigned r;
  asm("v_cvt_pk_bf16_f32 %0, %1, %2" : "=v"(r) : "v"(a), "v"(b));
  return r;
}

static __device__ __forceinline__ void gload_lds16(const void* g, void* l) {
  __builtin_amdgcn_global_load_lds(
      (const __attribute__((address_space(1))) unsigned int*)g,
      (__attribute__((address_space(3))) unsigned int*)l, 16, 0, 0);
}

// ---------------------------------------------------------------- fused prep
// blocks [0,4096): hs fp32 -> X bf16
// blocks [4096,8192): W transpose+convert -> WT
// blocks [8192,24576): tree_mask -> bitmask
__global__ __launch_bounds__(256) void prep_kernel(
    const float* __restrict__ hs, const int* __restrict__ mask,
    const float* __restrict__ Wq, const float* __restrict__ Wk,
    const float* __restrict__ Wv, const float* __restrict__ Wo,
    u16* __restrict__ X, u16* __restrict__ WT,
    unsigned long long* __restrict__ bits) {
  __shared__ float tile[32][33];
  const int bid = blockIdx.x;
  const int tid = threadIdx.x;
  if (bid < 4096) {
    const int i = bid * 256 + tid;
    const float4 v = reinterpret_cast<const float4*>(hs)[i];
    u16x4 o;
    o[0] = f2bf(v.x); o[1] = f2bf(v.y); o[2] = f2bf(v.z); o[3] = f2bf(v.w);
    reinterpret_cast<u16x4*>(X)[i] = o;
  } else if (bid < 8192) {
    const int B = bid - 4096;
    const int z = B >> 10, y = (B >> 5) & 31, x = B & 31;
    const float* src = (z == 0) ? Wq : (z == 1) ? Wk : (z == 2) ? Wv : Wo;
    u16* dst = WT + (size_t)z * 1024 * 1024;
    const int row0 = y * 32, col0 = x * 32;
    const int tx = tid & 31, ty = tid >> 5;
#pragma unroll
    for (int i = 0; i < 4; ++i)
      tile[ty + i * 8][tx] = src[(size_t)(row0 + ty + i * 8) * 1024 + col0 + tx];
    __syncthreads();
#pragma unroll
    for (int i = 0; i < 4; ++i) {
      const int r = ty + i * 8;
      dst[(size_t)(col0 + r) * 1024 + row0 + tx] = f2bf(tile[tx][r]);
    }
  } else {
    const int gw = (bid - 8192) * 4 + (tid >> 6);
    const int lane = tid & 63;
    const int q = gw >> 5, w = gw & 31;
    const int mv = mask[(size_t)q * 2048 + w * 64 + lane];
    const unsigned long long bal = __ballot(mv != 0);
    if (lane == 0) bits[(size_t)q * 32 + w] = bal;
  }
}

// ---------------------------------------------------------------- GEMM QKV
// Swapped-operand MFMA: D has m on l15 axis, n on register axis -> coalesced
// vectorized epilogue stores. Q rows pre-scaled by SCLOG (exp2 domain).
__global__ __launch_bounds__(256) void gemm_qkv_kernel(
    const u16* __restrict__ X, const u16* __restrict__ WT,
    const float* __restrict__ bq, const float* __restrict__ bk, const float* __restrict__ bv,
    u16* __restrict__ Qb, u16* __restrict__ Kb, u16* __restrict__ Vb) {
  __shared__ u16 As[128 * 32];
  __shared__ u16 Bs[128 * 32];
  const int tid = threadIdx.x;
  const int lane = tid & 63, wid = tid >> 6;
  const int l15 = lane & 15, lg = lane >> 4;
  const int n0 = blockIdx.x * 128, m0 = blockIdx.y * 128;
  const int wr = wid >> 1, wc = wid & 1;

  f32x4 acc[4][4] = {};

  for (int kt = 0; kt < 32; ++kt) {
    __syncthreads();
#pragma unroll
    for (int p = 0; p < 2; ++p) {
      const int c = p * 256 + tid;
      const int r = c >> 2, ch = c & 3;
      gload_lds16(X + (size_t)(m0 + r) * 1024 + kt * 32 + ch * 8,
                  &As[(p * 256 + wid * 64) * 8]);
      gload_lds16(WT + (size_t)(n0 + r) * 1024 + kt * 32 + ch * 8,
                  &Bs[(p * 256 + wid * 64) * 8]);
    }
    __syncthreads();
    short8 af[4], bfr[4];
#pragma unroll
    for (int i = 0; i < 4; ++i) {
      af[i] = *reinterpret_cast<const short8*>(&As[(wr * 64 + i * 16 + l15) * 32 + lg * 8]);
      bfr[i] = *reinterpret_cast<const short8*>(&Bs[(wc * 64 + i * 16 + l15) * 32 + lg * 8]);
    }
#pragma unroll
    for (int i = 0; i < 4; ++i)
#pragma unroll
      for (int j = 0; j < 4; ++j)
        acc[i][j] = __builtin_amdgcn_mfma_f32_16x16x32_bf16(bfr[j], af[i], acc[i][j], 0, 0, 0);
  }

#pragma unroll
  for (int i = 0; i < 4; ++i) {
    const int m = m0 + wr * 64 + i * 16 + l15;
    const int bb = m >> 11, t = m & 2047;
#pragma unroll
    for (int j = 0; j < 4; ++j) {
      const int n = n0 + wc * 64 + j * 16 + lg * 4;
      const float* bsrc = (n < 1024) ? (bq + n) : (n < 2048) ? (bk + n - 1024) : (bv + n - 2048);
      const float4 b4 = *reinterpret_cast<const float4*>(bsrc);
      const float scl = (n < 1024) ? SCLOG : 1.0f;
      u16* dst = (n < 1024) ? Qb : (n < 2048) ? Kb : Vb;
      const int nl = n & 1023;
      const int hh = nl >> 6, d0 = nl & 63;
      uint2 pk;
      pk.x = pk_bf16((acc[i][j][0] + b4.x) * scl, (acc[i][j][1] + b4.y) * scl);
      pk.y = pk_bf16((acc[i][j][2] + b4.z) * scl, (acc[i][j][3] + b4.w) * scl);
      *reinterpret_cast<uint2*>(dst + ((size_t)(bb * 16 + hh) * 2048 + t) * 64 + d0) = pk;
    }
  }
}

// ------------------------------------------------------------ V transpose
// Vb [32 bh][2048][64] -> VT [32 bh][64][2048]
__global__ __launch_bounds__(256) void transpose_v_kernel(const u16* __restrict__ Vb,
                                                          u16* __restrict__ VT) {
  __shared__ u16 tile[64][68];
  const int tid = threadIdx.x;
  const int tt = blockIdx.x & 31;
  const int bh = blockIdx.x >> 5;
  const size_t base = (size_t)bh * 2048 * 64;
  const int t0 = tt * 64;
#pragma unroll
  for (int p = 0; p < 2; ++p) {
    int i = p * 256 + tid;
    int row = i >> 3, ch = i & 7;
    *reinterpret_cast<short8*>(&tile[row][ch * 8]) =
        *reinterpret_cast<const short8*>(Vb + base + (size_t)(t0 + row) * 64 + ch * 8);
  }
  __syncthreads();
#pragma unroll
  for (int p = 0; p < 2; ++p) {
    int i = p * 256 + tid;
    int d = i >> 3, ch = i & 7;
    short8 v;
#pragma unroll
    for (int j = 0; j < 8; ++j) v[j] = tile[ch * 8 + j][d];
    *reinterpret_cast<short8*>(VT + base + (size_t)d * 2048 + t0 + ch * 8) = v;
  }
}

// ---------------------------------------------------------------- attention
struct AttnState {
  f32x4 O[4];
  float m, l;
  short8 qf0, qf1;
};

// one 64-k tile for one q-sub-tile state (Q pre-scaled: S already in exp2 domain)
static __device__ __forceinline__ void attn_tile(
    AttnState& st, const u16* __restrict__ Kb_, const u16* __restrict__ Vb_,
    u16* __restrict__ pwave, unsigned long long w,
    int l15, int lg, int slg) {
  f32x4 sT[4] = {};
  __builtin_amdgcn_s_setprio(1);
#pragma unroll
  for (int dc = 0; dc < 2; ++dc) {
    const short8 qv = dc ? st.qf1 : st.qf0;
#pragma unroll
    for (int sub = 0; sub < 4; ++sub) {
      const short8 kf = *reinterpret_cast<const short8*>(
          &Kb_[dc * 2048 + (sub * 16 + l15) * 32 + slg]);
      sT[sub] = __builtin_amdgcn_mfma_f32_16x16x32_bf16(kf, qv, sT[sub], 0, 0, 0);
    }
  }
  __builtin_amdgcn_s_setprio(0);

  float pm = -3e38f;
  if (__all(w == ~0ull)) {
#pragma unroll
    for (int sub = 0; sub < 4; ++sub)
#pragma unroll
      for (int r = 0; r < 4; ++r) pm = fmaxf(pm, sT[sub][r]);
  } else {
    const unsigned mlo = (unsigned)w, mhi = (unsigned)(w >> 32);
#pragma unroll
    for (int sub = 0; sub < 4; ++sub) {
      const unsigned f = ((sub & 2) ? mhi : mlo) >> ((sub & 1) * 16 + lg * 4);
#pragma unroll
      for (int r = 0; r < 4; ++r) {
        const float val = ((f >> r) & 1u) ? sT[sub][r] : -1e30f;
        sT[sub][r] = val;
        pm = fmaxf(pm, val);
      }
    }
  }
  pm = fmaxf(pm, __shfl_xor(pm, 16));
  pm = fmaxf(pm, __shfl_xor(pm, 32));
  // defer-max (T13, THR=8 in log2 units)
  if (!__all(pm - st.m <= 8.f)) {
    const float mn = fmaxf(st.m, pm);
    const float al = exp2f(st.m - mn);
    st.m = mn;
    st.l *= al;
#pragma unroll
    for (int dt = 0; dt < 4; ++dt) st.O[dt] *= al;
  }

  float lsum = 0.f;
#pragma unroll
  for (int kc = 0; kc < 2; ++kc) {
#pragma unroll
    for (int s2 = 0; s2 < 2; ++s2) {
      const int sub = kc * 2 + s2;
      const float e0 = exp2f(sT[sub][0] - st.m);
      const float e1 = exp2f(sT[sub][1] - st.m);
      const float e2 = exp2f(sT[sub][2] - st.m);
      const float e3 = exp2f(sT[sub][3] - st.m);
      lsum += (e0 + e1) + (e2 + e3);
      uint2 pk;
      pk.x = pk_bf16(e0, e1);
      pk.y = pk_bf16(e2, e3);
      *reinterpret_cast<uint2*>(&pwave[l15 * 40 + s2 * 16 + lg * 4]) = pk;
    }
    const short8 pf = *reinterpret_cast<const short8*>(&pwave[l15 * 40 + lg * 8]);
    __builtin_amdgcn_s_setprio(1);
#pragma unroll
    for (int dt = 0; dt < 4; ++dt) {
      const short8 vf = *reinterpret_cast<const short8*>(
          &Vb_[kc * 2048 + (dt * 16 + l15) * 32 + slg]);
      st.O[dt] = __builtin_amdgcn_mfma_f32_16x16x32_bf16(vf, pf, st.O[dt], 0, 0, 0);
    }
    __builtin_amdgcn_s_setprio(0);
  }
  lsum += __shfl_xor(lsum, 16);
  lsum += __shfl_xor(lsum, 32);
  st.l += lsum;
}

// Q/K [2][16][2048][64] bf16 ; VT [2][16][64][2048] bf16 ; MB [2048][32] u64
// AO [4096][1024] bf16.  Block = (pair, h, b): q-tiles qp and 31-qp share staging.
__global__ __launch_bounds__(256, 4) void attn_kernel(
    const u16* __restrict__ Q, const u16* __restrict__ K, const u16* __restrict__ VT,
    const unsigned long long* __restrict__ MB, u16* __restrict__ AO) {
  __shared__ u16 K_lds[2][4096];
  __shared__ u16 V_lds[2][4096];
  __shared__ u16 p_lds[4][16][40];
  __shared__ unsigned actA_s, actB_s;

  const int tid = threadIdx.x;
  const int wid = tid >> 6, lane = tid & 63;
  const int l15 = lane & 15, lg = lane >> 4;

  const int qp = blockIdx.x;          // 0..15
  const int qA_t = qp, qB_t = 31 - qp;
  const int h = blockIdx.y;
  const int b = blockIdx.z;
  const size_t bh_off = ((size_t)(b * 16 + h)) * 2048 * 64;

  if (tid == 0) { actA_s = 0; actB_s = 0; }
  __syncthreads();
  {
    const int ktc = tid & 31, qg = tid >> 5;
    unsigned long long orA = 0, orB = 0;
#pragma unroll
    for (int i = 0; i < 8; ++i) {
      orA |= MB[(size_t)(qA_t * 64 + qg * 8 + i) * 32 + ktc];
      orB |= MB[(size_t)(qB_t * 64 + qg * 8 + i) * 32 + ktc];
    }
    if (orA) atomicOr(&actA_s, 1u << ktc);
    if (orB) atomicOr(&actB_s, 1u << ktc);
  }

  const int qa = qA_t * 64 + wid * 16 + l15;
  const int qb = qB_t * 64 + wid * 16 + l15;

  AttnState stA, stB;
  {
    const short8* qpA = reinterpret_cast<const short8*>(Q + bh_off + (size_t)qa * 64);
    const short8* qpB = reinterpret_cast<const short8*>(Q + bh_off + (size_t)qb * 64);
    stA.qf0 = qpA[lg]; stA.qf1 = qpA[4 + lg];
    stB.qf0 = qpB[lg]; stB.qf1 = qpB[4 + lg];
#pragma unroll
    for (int dt = 0; dt < 4; ++dt) { stA.O[dt] = f32x4{}; stB.O[dt] = f32x4{}; }
    stA.m = -3e38f; stA.l = 0.f;
    stB.m = -3e38f; stB.l = 0.f;
  }

  const int slg = (lg ^ ((l15 >> 1) & 3)) * 8;

  int offK[2], offV[2], ldsi[2];
#pragma unroll
  for (int p = 0; p < 2; ++p) {
    const int i = wid * 128 + p * 64 + lane;
    const int pc = i >> 8, row = (i >> 2) & 63, lgc = i & 3;
    const int lgs = lgc ^ ((i >> 3) & 3);
    offK[p] = row * 64 + pc * 32 + lgs * 8;
    offV[p] = row * 2048 + pc * 32 + lgs * 8;
    ldsi[p] = (wid * 128 + p * 64) * 8;
  }
  const u16* Kg = K + bh_off;
  const u16* Vg = VT + bh_off;
  u16* pwave = &p_lds[wid][0][0];

  __syncthreads();
  const unsigned actA = actA_s, actB = actB_s;
  unsigned rem = actA | actB;
  int buf = 0;

#define STAGE_TILE(bb, ktv)                                        \
  do {                                                             \
    const u16* ksrc_ = Kg + (ktv) * 64 * 64;                       \
    const u16* vsrc_ = Vg + (ktv) * 64;                            \
    _Pragma("unroll") for (int p_ = 0; p_ < 2; ++p_) {             \
      gload_lds16(ksrc_ + offK[p_], &K_lds[bb][ldsi[p_]]);         \
      gload_lds16(vsrc_ + offV[p_], &V_lds[bb][ldsi[p_]]);         \
    }                                                              \
  } while (0)

  if (rem) {
    int kt = __ffs(rem) - 1;
    unsigned long long wA_cur = MB[(size_t)qa * 32 + kt];
    unsigned long long wB_cur = MB[(size_t)qb * 32 + kt];
    STAGE_TILE(0, kt);
    __syncthreads();

    while (true) {
      rem &= rem - 1;
      int ktn = -1;
      unsigned long long wA_next = 0, wB_next = 0;
      if (rem) {
        ktn = __ffs(rem) - 1;
        wA_next = MB[(size_t)qa * 32 + ktn];
        wB_next = MB[(size_t)qb * 32 + ktn];
        STAGE_TILE(buf ^ 1, ktn);
      }

      if ((actB >> kt) & 1u)
        attn_tile(stB, &K_lds[buf][0], &V_lds[buf][0], pwave, wB_cur, l15, lg, slg);
      if ((actA >> kt) & 1u)
        attn_tile(stA, &K_lds[buf][0], &V_lds[buf][0], pwave, wA_cur, l15, lg, slg);

      if (ktn < 0) break;
      __syncthreads();
      buf ^= 1;
      kt = ktn;
      wA_cur = wA_next;
      wB_cur = wB_next;
    }
  }
#undef STAGE_TILE

  {
    const float invA = (stA.l > 0.f) ? (1.0f / stA.l) : 0.f;
    u16* dstA = AO + ((size_t)(b * 2048 + qa)) * 1024 + h * 64;
#pragma unroll
    for (int dt = 0; dt < 4; ++dt) {
      uint2 pk;
      pk.x = pk_bf16(stA.O[dt][0] * invA, stA.O[dt][1] * invA);
      pk.y = pk_bf16(stA.O[dt][2] * invA, stA.O[dt][3] * invA);
      *reinterpret_cast<uint2*>(dstA + dt * 16 + lg * 4) = pk;
    }
    const float invB = (stB.l > 0.f) ? (1.0f / stB.l) : 0.f;
    u16* dstB = AO + ((size_t)(b * 2048 + qb)) * 1024 + h * 64;
#pragma unroll
    for (int dt = 0; dt < 4; ++dt) {
      uint2 pk;
      pk.x = pk_bf16(stB.O[dt][0] * invB, stB.O[dt][1] * invB);
      pk.y = pk_bf16(stB.O[dt][2] * invB, stB.O[dt][3] * invB);
      *reinterpret_cast<uint2*>(dstB + dt * 16 + lg * 4) = pk;
    }
  }
}

// ---------------------------------------------------------------- out GEMM
// Swapped-operand MFMA -> n on register axis -> float4 stores.
__global__ __launch_bounds__(256) void gemm_out_kernel(
    const u16* __restrict__ A, const u16* __restrict__ BT,
    const float* __restrict__ bo, float* __restrict__ out) {
  __shared__ u16 As[128 * 32];
  __shared__ u16 Bs[128 * 32];
  const int tid = threadIdx.x;
  const int lane = tid & 63, wid = tid >> 6;
  const int l15 = lane & 15, lg = lane >> 4;
  const int n0 = blockIdx.x * 128, m0 = blockIdx.y * 128;
  const int wr = wid >> 1, wc = wid & 1;

  f32x4 acc[4][4] = {};

  for (int kt = 0; kt < 32; ++kt) {
    __syncthreads();
#pragma unroll
    for (int p = 0; p < 2; ++p) {
      const int c = p * 256 + tid;
      const int r = c >> 2, ch = c & 3;
      gload_lds16(A + (size_t)(m0 + r) * 1024 + kt * 32 + ch * 8,
                  &As[(p * 256 + wid * 64) * 8]);
      gload_lds16(BT + (size_t)(n0 + r) * 1024 + kt * 32 + ch * 8,
                  &Bs[(p * 256 + wid * 64) * 8]);
    }
    __syncthreads();
    short8 af[4], bfr[4];
#pragma unroll
    for (int i = 0; i < 4; ++i) {
      af[i] = *reinterpret_cast<const short8*>(&As[(wr * 64 + i * 16 + l15) * 32 + lg * 8]);
      bfr[i] = *reinterpret_cast<const short8*>(&Bs[(wc * 64 + i * 16 + l15) * 32 + lg * 8]);
    }
#pragma unroll
    for (int i = 0; i < 4; ++i)
#pragma unroll
      for (int j = 0; j < 4; ++j)
        acc[i][j] = __builtin_amdgcn_mfma_f32_16x16x32_bf16(bfr[j], af[i], acc[i][j], 0, 0, 0);
  }

#pragma unroll
  for (int i = 0; i < 4; ++i) {
    const int m = m0 + wr * 64 + i * 16 + l15;
#pragma unroll
    for (int j = 0; j < 4; ++j) {
      const int n = n0 + wc * 64 + j * 16 + lg * 4;
      const float4 b4 = *reinterpret_cast<const float4*>(bo + n);
      float4 o4;
      o4.x = acc[i][j][0] + b4.x;
      o4.y = acc[i][j][1] + b4.y;
      o4.z = acc[i][j][2] + b4.z;
      o4.w = acc[i][j][3] + b4.w;
      *reinterpret_cast<float4*>(out + (size_t)m * 1024 + n) = o4;
    }
  }
}

// ---------------------------------------------------------------- launcher
extern "C" void kernel_launch(void* const* d_in, const int* in_sizes, int n_in,
                              void* d_out, int out_size, void* d_ws, size_t ws_size,
                              hipStream_t stream) {
  (void)in_sizes; (void)n_in; (void)out_size; (void)ws_size;
  const float* hs = (const float*)d_in[0];
  const int* mask = (const int*)d_in[1];
  const float* Wq = (const float*)d_in[2];
  const float* bq = (const float*)d_in[3];
  const float* Wk = (const float*)d_in[4];
  const float* bk = (const float*)d_in[5];
  const float* Wv = (const float*)d_in[6];
  const float* bv = (const float*)d_in[7];
  const float* Wo = (const float*)d_in[8];
  const float* bo = (const float*)d_in[9];
  float* out = (float*)d_out;

  uint8_t* ws = (uint8_t*)d_ws;
  u16* X  = (u16*)(ws);                          // 8 MiB (dead after gemm_qkv)
  u16* WT = (u16*)(ws + ((size_t)8 << 20));      // 8 MiB
  u16* Qb = (u16*)(ws + ((size_t)16 << 20));     // 8 MiB
  u16* Kb = (u16*)(ws + ((size_t)24 << 20));     // 8 MiB
  u16* Vb = (u16*)(ws + ((size_t)32 << 20));     // 8 MiB
  u16* AO = (u16*)(ws + ((size_t)40 << 20));     // 8 MiB
  unsigned long long* MB = (unsigned long long*)(ws + ((size_t)48 << 20));  // 512 KiB
  u16* VbT = X;                                  // reuse X region for V^T

  prep_kernel<<<dim3(24576), dim3(256), 0, stream>>>(hs, mask, Wq, Wk, Wv, Wo, X, WT, MB);
  gemm_qkv_kernel<<<dim3(24, 32), dim3(256), 0, stream>>>(X, WT, bq, bk, bv, Qb, Kb, Vb);
  transpose_v_kernel<<<dim3(1024), dim3(256), 0, stream>>>(Vb, VbT);
  attn_kernel<<<dim3(16, 16, 2), dim3(256), 0, stream>>>(Qb, Kb, VbT, MB, AO);
  gemm_out_kernel<<<dim3(8, 32), dim3(256), 0, stream>>>(AO, WT + (size_t)3072 * 1024, bo, out);
}

// Round 7
// 143.625 us; speedup vs baseline: 2.2501x; 1.0229x over previous
//
#include <hip/hip_runtime.h>
#include <hip/hip_bf16.h>
#include <stdint.h>

typedef unsigned short u16;
typedef short short8 __attribute__((ext_vector_type(8)));
typedef float f32x4 __attribute__((ext_vector_type(4)));
typedef u16 u16x4 __attribute__((ext_vector_type(4)));

#define SCLOG 0.18033688011112042f  // 0.125 * log2(e)

// fp32 -> bf16 RNE (values are finite; no NaN handling needed)
static __device__ __forceinline__ u16 f2bf(float f) {
  unsigned u = __float_as_uint(f);
  unsigned rnd = 0x7fffu + ((u >> 16) & 1u);
  return (u16)((u + rnd) >> 16);
}

// packed f32x2 -> bf16x2 via HW v_cvt_pk_bf16_f32 (no builtin on gfx950; T12/m240)
static __device__ __forceinline__ unsigned pk_bf16(float a, float b) {
  unsigned r;
  asm("v_cvt_pk_bf16_f32 %0, %1, %2" : "=v"(r) : "v"(a), "v"(b));
  return r;
}

static __device__ __forceinline__ void gload_lds16(const void* g, void* l) {
  __builtin_amdgcn_global_load_lds(
      (const __attribute__((address_space(1))) unsigned int*)g,
      (__attribute__((address_space(3))) unsigned int*)l, 16, 0, 0);
}

// ---------------------------------------------------------------- fused prep
__global__ __launch_bounds__(256) void prep_kernel(
    const float* __restrict__ hs, const int* __restrict__ mask,
    const float* __restrict__ Wq, const float* __restrict__ Wk,
    const float* __restrict__ Wv, const float* __restrict__ Wo,
    u16* __restrict__ X, u16* __restrict__ WT,
    unsigned long long* __restrict__ bits) {
  __shared__ float tile[32][33];
  const int bid = blockIdx.x;
  const int tid = threadIdx.x;
  if (bid < 4096) {
    const int i = bid * 256 + tid;
    const float4 v = reinterpret_cast<const float4*>(hs)[i];
    u16x4 o;
    o[0] = f2bf(v.x); o[1] = f2bf(v.y); o[2] = f2bf(v.z); o[3] = f2bf(v.w);
    reinterpret_cast<u16x4*>(X)[i] = o;
  } else if (bid < 8192) {
    const int B = bid - 4096;
    const int z = B >> 10, y = (B >> 5) & 31, x = B & 31;
    const float* src = (z == 0) ? Wq : (z == 1) ? Wk : (z == 2) ? Wv : Wo;
    u16* dst = WT + (size_t)z * 1024 * 1024;
    const int row0 = y * 32, col0 = x * 32;
    const int tx = tid & 31, ty = tid >> 5;
#pragma unroll
    for (int i = 0; i < 4; ++i)
      tile[ty + i * 8][tx] = src[(size_t)(row0 + ty + i * 8) * 1024 + col0 + tx];
    __syncthreads();
#pragma unroll
    for (int i = 0; i < 4; ++i) {
      const int r = ty + i * 8;
      dst[(size_t)(col0 + r) * 1024 + row0 + tx] = f2bf(tile[tx][r]);
    }
  } else {
    const int gw = (bid - 8192) * 4 + (tid >> 6);
    const int lane = tid & 63;
    const int q = gw >> 5, w = gw & 31;
    const int mv = mask[(size_t)q * 2048 + w * 64 + lane];
    const unsigned long long bal = __ballot(mv != 0);
    if (lane == 0) bits[(size_t)q * 32 + w] = bal;
  }
}

// ---------------------------------------------------------------- GEMM QKV
__global__ __launch_bounds__(256) void gemm_qkv_kernel(
    const u16* __restrict__ X, const u16* __restrict__ WT,
    const float* __restrict__ bq, const float* __restrict__ bk, const float* __restrict__ bv,
    u16* __restrict__ Qb, u16* __restrict__ Kb, u16* __restrict__ Vb) {
  __shared__ u16 As[128 * 32];
  __shared__ u16 Bs[128 * 32];
  const int tid = threadIdx.x;
  const int lane = tid & 63, wid = tid >> 6;
  const int l15 = lane & 15, lg = lane >> 4;
  const int n0 = blockIdx.x * 128, m0 = blockIdx.y * 128;
  const int wr = wid >> 1, wc = wid & 1;

  f32x4 acc[4][4] = {};

  for (int kt = 0; kt < 32; ++kt) {
    __syncthreads();
#pragma unroll
    for (int p = 0; p < 2; ++p) {
      const int c = p * 256 + tid;
      const int r = c >> 2, ch = c & 3;
      gload_lds16(X + (size_t)(m0 + r) * 1024 + kt * 32 + ch * 8,
                  &As[(p * 256 + wid * 64) * 8]);
      gload_lds16(WT + (size_t)(n0 + r) * 1024 + kt * 32 + ch * 8,
                  &Bs[(p * 256 + wid * 64) * 8]);
    }
    __syncthreads();
    short8 af[4], bfr[4];
#pragma unroll
    for (int i = 0; i < 4; ++i) {
      af[i] = *reinterpret_cast<const short8*>(&As[(wr * 64 + i * 16 + l15) * 32 + lg * 8]);
      bfr[i] = *reinterpret_cast<const short8*>(&Bs[(wc * 64 + i * 16 + l15) * 32 + lg * 8]);
    }
#pragma unroll
    for (int i = 0; i < 4; ++i)
#pragma unroll
      for (int j = 0; j < 4; ++j)
        acc[i][j] = __builtin_amdgcn_mfma_f32_16x16x32_bf16(bfr[j], af[i], acc[i][j], 0, 0, 0);
  }

#pragma unroll
  for (int i = 0; i < 4; ++i) {
    const int m = m0 + wr * 64 + i * 16 + l15;
    const int bb = m >> 11, t = m & 2047;
#pragma unroll
    for (int j = 0; j < 4; ++j) {
      const int n = n0 + wc * 64 + j * 16 + lg * 4;
      const float* bsrc = (n < 1024) ? (bq + n) : (n < 2048) ? (bk + n - 1024) : (bv + n - 2048);
      const float4 b4 = *reinterpret_cast<const float4*>(bsrc);
      const float scl = (n < 1024) ? SCLOG : 1.0f;
      u16* dst = (n < 1024) ? Qb : (n < 2048) ? Kb : Vb;
      const int nl = n & 1023;
      const int hh = nl >> 6, d0 = nl & 63;
      uint2 pk;
      pk.x = pk_bf16((acc[i][j][0] + b4.x) * scl, (acc[i][j][1] + b4.y) * scl);
      pk.y = pk_bf16((acc[i][j][2] + b4.z) * scl, (acc[i][j][3] + b4.w) * scl);
      *reinterpret_cast<uint2*>(dst + ((size_t)(bb * 16 + hh) * 2048 + t) * 64 + d0) = pk;
    }
  }
}

// ------------------------------------------------------------ V transpose
__global__ __launch_bounds__(256) void transpose_v_kernel(const u16* __restrict__ Vb,
                                                          u16* __restrict__ VT) {
  __shared__ u16 tile[64][68];
  const int tid = threadIdx.x;
  const int tt = blockIdx.x & 31;
  const int bh = blockIdx.x >> 5;
  const size_t base = (size_t)bh * 2048 * 64;
  const int t0 = tt * 64;
#pragma unroll
  for (int p = 0; p < 2; ++p) {
    int i = p * 256 + tid;
    int row = i >> 3, ch = i & 7;
    *reinterpret_cast<short8*>(&tile[row][ch * 8]) =
        *reinterpret_cast<const short8*>(Vb + base + (size_t)(t0 + row) * 64 + ch * 8);
  }
  __syncthreads();
#pragma unroll
  for (int p = 0; p < 2; ++p) {
    int i = p * 256 + tid;
    int d = i >> 3, ch = i & 7;
    short8 v;
#pragma unroll
    for (int j = 0; j < 8; ++j) v[j] = tile[ch * 8 + j][d];
    *reinterpret_cast<short8*>(VT + base + (size_t)d * 2048 + t0 + ch * 8) = v;
  }
}

// ---------------------------------------------------------------- attention
struct AttnState {
  f32x4 O[4];
  float m, l;     // l is a PER-LANE partial (reduced across lg at epilogue)
  short8 qf0, qf1;
};

// one 64-k tile for one wave's 16 q-rows (Q pre-scaled: S already in exp2 domain)
static __device__ __forceinline__ void attn_tile(
    AttnState& st, const u16* __restrict__ Kb_, const u16* __restrict__ Vb_,
    u16* __restrict__ pwave, unsigned long long w,
    int l15, int lg, int slg) {
  f32x4 sT[4] = {};
  __builtin_amdgcn_s_setprio(1);
#pragma unroll
  for (int dc = 0; dc < 2; ++dc) {
    const short8 qv = dc ? st.qf1 : st.qf0;
#pragma unroll
    for (int sub = 0; sub < 4; ++sub) {
      const short8 kf = *reinterpret_cast<const short8*>(
          &Kb_[dc * 2048 + (sub * 16 + l15) * 32 + slg]);
      sT[sub] = __builtin_amdgcn_mfma_f32_16x16x32_bf16(kf, qv, sT[sub], 0, 0, 0);
    }
  }
  __builtin_amdgcn_s_setprio(0);

  if (!__all(w == ~0ull)) {
    const unsigned mlo = (unsigned)w, mhi = (unsigned)(w >> 32);
#pragma unroll
    for (int sub = 0; sub < 4; ++sub) {
      const unsigned f = ((sub & 2) ? mhi : mlo) >> ((sub & 1) * 16 + lg * 4);
#pragma unroll
      for (int r = 0; r < 4; ++r)
        sT[sub][r] = ((f >> r) & 1u) ? sT[sub][r] : -1e30f;
    }
  }
  // tree max (depth 4; v_max3-friendly)
  float pm;
  {
    const float t0 = fmaxf(fmaxf(sT[0][0], sT[0][1]), fmaxf(sT[0][2], sT[0][3]));
    const float t1 = fmaxf(fmaxf(sT[1][0], sT[1][1]), fmaxf(sT[1][2], sT[1][3]));
    const float t2 = fmaxf(fmaxf(sT[2][0], sT[2][1]), fmaxf(sT[2][2], sT[2][3]));
    const float t3 = fmaxf(fmaxf(sT[3][0], sT[3][1]), fmaxf(sT[3][2], sT[3][3]));
    pm = fmaxf(fmaxf(t0, t1), fmaxf(t2, t3));
  }
  pm = fmaxf(pm, __shfl_xor(pm, 16));
  pm = fmaxf(pm, __shfl_xor(pm, 32));
  // defer-max (T13, THR=8 in log2 units)
  if (!__all(pm - st.m <= 8.f)) {
    const float mn = fmaxf(st.m, pm);
    const float al = exp2f(st.m - mn);
    st.m = mn;
    st.l *= al;
#pragma unroll
    for (int dt = 0; dt < 4; ++dt) st.O[dt] *= al;
  }

  float lsum = 0.f;
#pragma unroll
  for (int kc = 0; kc < 2; ++kc) {
#pragma unroll
    for (int s2 = 0; s2 < 2; ++s2) {
      const int sub = kc * 2 + s2;
      const float e0 = exp2f(sT[sub][0] - st.m);
      const float e1 = exp2f(sT[sub][1] - st.m);
      const float e2 = exp2f(sT[sub][2] - st.m);
      const float e3 = exp2f(sT[sub][3] - st.m);
      lsum += (e0 + e1) + (e2 + e3);
      uint2 pk;
      pk.x = pk_bf16(e0, e1);
      pk.y = pk_bf16(e2, e3);
      *reinterpret_cast<uint2*>(&pwave[l15 * 40 + s2 * 16 + lg * 4]) = pk;
    }
    const short8 pf = *reinterpret_cast<const short8*>(&pwave[l15 * 40 + lg * 8]);
    __builtin_amdgcn_s_setprio(1);
#pragma unroll
    for (int dt = 0; dt < 4; ++dt) {
      const short8 vf = *reinterpret_cast<const short8*>(
          &Vb_[kc * 2048 + (dt * 16 + l15) * 32 + slg]);
      st.O[dt] = __builtin_amdgcn_mfma_f32_16x16x32_bf16(vf, pf, st.O[dt], 0, 0, 0);
    }
    __builtin_amdgcn_s_setprio(0);
  }
  st.l += lsum;  // per-lane partial; reduced at epilogue
}

// Q/K [2][16][2048][64] bf16 ; VT [2][16][64][2048] bf16 ; MB [2048][32] u64
// AO [4096][1024] bf16.
// Block = one 32-row q-tile PAIR (qp, 63-qp): waves 0-1 own state A, waves 2-3
// own state B. Grid 1024 = 4 blocks/CU. XCD swizzle groups all 32 pair-blocks
// of one (h,b) onto one XCD so its 512KB K/V stays L2-local.
__global__ __launch_bounds__(256, 4) void attn_kernel(
    const u16* __restrict__ Q, const u16* __restrict__ K, const u16* __restrict__ VT,
    const unsigned long long* __restrict__ MB, u16* __restrict__ AO) {
  __shared__ u16 K_lds[2][4096];
  __shared__ u16 V_lds[2][4096];
  __shared__ u16 p_lds[4][16][40];
  __shared__ unsigned actA_s, actB_s;

  const int tid = threadIdx.x;
  const int wid = tid >> 6, lane = tid & 63;
  const int l15 = lane & 15, lg = lane >> 4;

  // XCD-grouping decode: wgid = (g%8) + 8*((g/8)*32 + qp)
  const int wgid = blockIdx.x;          // 0..1023
  const int x = wgid & 7, s = wgid >> 3;
  const int g = x + 8 * (s >> 5);       // (h,b) group 0..31
  const int qp = s & 31;                // pair 0..31
  const int h = g & 15, b = g >> 4;
  const int qA_t = qp, qB_t = 63 - qp;  // 32-row q-tiles
  const size_t bh_off = ((size_t)(b * 16 + h)) * 2048 * 64;

  if (tid == 0) { actA_s = 0; actB_s = 0; }
  __syncthreads();
  {
    const int ktc = tid & 31, rg = tid >> 5;  // 8 row-groups of 4 rows
    unsigned long long orA = 0, orB = 0;
#pragma unroll
    for (int i = 0; i < 4; ++i) {
      orA |= MB[(size_t)(qA_t * 32 + rg * 4 + i) * 32 + ktc];
      orB |= MB[(size_t)(qB_t * 32 + rg * 4 + i) * 32 + ktc];
    }
    if (orA) atomicOr(&actA_s, 1u << ktc);
    if (orB) atomicOr(&actB_s, 1u << ktc);
  }

  // wave -> state mapping
  const int sid = wid >> 1;                       // 0 = A, 1 = B
  const int qt = sid ? qB_t : qA_t;
  const int q = qt * 32 + (wid & 1) * 16 + l15;   // this wave's q-row

  AttnState st;
  {
    const short8* qp_ = reinterpret_cast<const short8*>(Q + bh_off + (size_t)q * 64);
    st.qf0 = qp_[lg]; st.qf1 = qp_[4 + lg];
#pragma unroll
    for (int dt = 0; dt < 4; ++dt) st.O[dt] = f32x4{};
    st.m = -3e38f; st.l = 0.f;
  }

  const int slg = (lg ^ ((l15 >> 1) & 3)) * 8;

  int offK[2], offV[2], ldsi[2];
#pragma unroll
  for (int p = 0; p < 2; ++p) {
    const int i = wid * 128 + p * 64 + lane;
    const int pc = i >> 8, row = (i >> 2) & 63, lgc = i & 3;
    const int lgs = lgc ^ ((i >> 3) & 3);
    offK[p] = row * 64 + pc * 32 + lgs * 8;
    offV[p] = row * 2048 + pc * 32 + lgs * 8;
    ldsi[p] = (wid * 128 + p * 64) * 8;
  }
  const u16* Kg = K + bh_off;
  const u16* Vg = VT + bh_off;
  u16* pwave = &p_lds[wid][0][0];

  __syncthreads();
  const unsigned actA = actA_s, actB = actB_s;
  const unsigned actW = sid ? actB : actA;
  unsigned rem = actA | actB;
  int buf = 0;

#define STAGE_TILE(bb, ktv)                                        \
  do {                                                             \
    const u16* ksrc_ = Kg + (ktv) * 64 * 64;                       \
    const u16* vsrc_ = Vg + (ktv) * 64;                            \
    _Pragma("unroll") for (int p_ = 0; p_ < 2; ++p_) {             \
      gload_lds16(ksrc_ + offK[p_], &K_lds[bb][ldsi[p_]]);         \
      gload_lds16(vsrc_ + offV[p_], &V_lds[bb][ldsi[p_]]);         \
    }                                                              \
  } while (0)

  if (rem) {
    int kt = __ffs(rem) - 1;
    unsigned long long w_cur = MB[(size_t)q * 32 + kt];
    STAGE_TILE(0, kt);
    __syncthreads();

    while (true) {
      rem &= rem - 1;
      int ktn = -1;
      unsigned long long w_next = 0;
      if (rem) {
        ktn = __ffs(rem) - 1;
        w_next = MB[(size_t)q * 32 + ktn];
        STAGE_TILE(buf ^ 1, ktn);
      }

      if ((actW >> kt) & 1u)
        attn_tile(st, &K_lds[buf][0], &V_lds[buf][0], pwave, w_cur, l15, lg, slg);

      if (ktn < 0) break;
      __syncthreads();
      buf ^= 1;
      kt = ktn;
      w_cur = w_next;
    }
  }
#undef STAGE_TILE

  // epilogue: reduce per-lane l across the 4 lg groups, normalize, store
  {
    float lr = st.l;
    lr += __shfl_xor(lr, 16);
    lr += __shfl_xor(lr, 32);
    const float inv = (lr > 0.f) ? (1.0f / lr) : 0.f;
    u16* dst = AO + ((size_t)(b * 2048 + q)) * 1024 + h * 64;
#pragma unroll
    for (int dt = 0; dt < 4; ++dt) {
      uint2 pk;
      pk.x = pk_bf16(st.O[dt][0] * inv, st.O[dt][1] * inv);
      pk.y = pk_bf16(st.O[dt][2] * inv, st.O[dt][3] * inv);
      *reinterpret_cast<uint2*>(dst + dt * 16 + lg * 4) = pk;
    }
  }
}

// ---------------------------------------------------------------- out GEMM
__global__ __launch_bounds__(256) void gemm_out_kernel(
    const u16* __restrict__ A, const u16* __restrict__ BT,
    const float* __restrict__ bo, float* __restrict__ out) {
  __shared__ u16 As[128 * 32];
  __shared__ u16 Bs[128 * 32];
  const int tid = threadIdx.x;
  const int lane = tid & 63, wid = tid >> 6;
  const int l15 = lane & 15, lg = lane >> 4;
  const int n0 = blockIdx.x * 128, m0 = blockIdx.y * 128;
  const int wr = wid >> 1, wc = wid & 1;

  f32x4 acc[4][4] = {};

  for (int kt = 0; kt < 32; ++kt) {
    __syncthreads();
#pragma unroll
    for (int p = 0; p < 2; ++p) {
      const int c = p * 256 + tid;
      const int r = c >> 2, ch = c & 3;
      gload_lds16(A + (size_t)(m0 + r) * 1024 + kt * 32 + ch * 8,
                  &As[(p * 256 + wid * 64) * 8]);
      gload_lds16(BT + (size_t)(n0 + r) * 1024 + kt * 32 + ch * 8,
                  &Bs[(p * 256 + wid * 64) * 8]);
    }
    __syncthreads();
    short8 af[4], bfr[4];
#pragma unroll
    for (int i = 0; i < 4; ++i) {
      af[i] = *reinterpret_cast<const short8*>(&As[(wr * 64 + i * 16 + l15) * 32 + lg * 8]);
      bfr[i] = *reinterpret_cast<const short8*>(&Bs[(wc * 64 + i * 16 + l15) * 32 + lg * 8]);
    }
#pragma unroll
    for (int i = 0; i < 4; ++i)
#pragma unroll
      for (int j = 0; j < 4; ++j)
        acc[i][j] = __builtin_amdgcn_mfma_f32_16x16x32_bf16(bfr[j], af[i], acc[i][j], 0, 0, 0);
  }

#pragma unroll
  for (int i = 0; i < 4; ++i) {
    const int m = m0 + wr * 64 + i * 16 + l15;
#pragma unroll
    for (int j = 0; j < 4; ++j) {
      const int n = n0 + wc * 64 + j * 16 + lg * 4;
      const float4 b4 = *reinterpret_cast<const float4*>(bo + n);
      float4 o4;
      o4.x = acc[i][j][0] + b4.x;
      o4.y = acc[i][j][1] + b4.y;
      o4.z = acc[i][j][2] + b4.z;
      o4.w = acc[i][j][3] + b4.w;
      *reinterpret_cast<float4*>(out + (size_t)m * 1024 + n) = o4;
    }
  }
}

// ---------------------------------------------------------------- launcher
extern "C" void kernel_launch(void* const* d_in, const int* in_sizes, int n_in,
                              void* d_out, int out_size, void* d_ws, size_t ws_size,
                              hipStream_t stream) {
  (void)in_sizes; (void)n_in; (void)out_size; (void)ws_size;
  const float* hs = (const float*)d_in[0];
  const int* mask = (const int*)d_in[1];
  const float* Wq = (const float*)d_in[2];
  const float* bq = (const float*)d_in[3];
  const float* Wk = (const float*)d_in[4];
  const float* bk = (const float*)d_in[5];
  const float* Wv = (const float*)d_in[6];
  const float* bv = (const float*)d_in[7];
  const float* Wo = (const float*)d_in[8];
  const float* bo = (const float*)d_in[9];
  float* out = (float*)d_out;

  uint8_t* ws = (uint8_t*)d_ws;
  u16* X  = (u16*)(ws);                          // 8 MiB (dead after gemm_qkv)
  u16* WT = (u16*)(ws + ((size_t)8 << 20));      // 8 MiB
  u16* Qb = (u16*)(ws + ((size_t)16 << 20));     // 8 MiB
  u16* Kb = (u16*)(ws + ((size_t)24 << 20));     // 8 MiB
  u16* Vb = (u16*)(ws + ((size_t)32 << 20));     // 8 MiB
  u16* AO = (u16*)(ws + ((size_t)40 << 20));     // 8 MiB
  unsigned long long* MB = (unsigned long long*)(ws + ((size_t)48 << 20));  // 512 KiB
  u16* VbT = X;                                  // reuse X region for V^T

  prep_kernel<<<dim3(24576), dim3(256), 0, stream>>>(hs, mask, Wq, Wk, Wv, Wo, X, WT, MB);
  gemm_qkv_kernel<<<dim3(24, 32), dim3(256), 0, stream>>>(X, WT, bq, bk, bv, Qb, Kb, Vb);
  transpose_v_kernel<<<dim3(1024), dim3(256), 0, stream>>>(Vb, VbT);
  attn_kernel<<<dim3(1024), dim3(256), 0, stream>>>(Qb, Kb, VbT, MB, AO);
  gemm_out_kernel<<<dim3(8, 32), dim3(256), 0, stream>>>(AO, WT + (size_t)3072 * 1024, bo, out);
}